// Round 2
// baseline (939.084 us; speedup 1.0000x reference)
//
#include <hip/hip_runtime.h>
#include <hip/hip_bf16.h>
#include <math.h>

#define N_NODES 50000
#define N_EDGES 800000
#define IN_DIM  128
#define HC_DIM  128
#define HID_C   32
#define SCAN_NB 196   // ceil(50000/256)

__device__ __forceinline__ float gelu_f(float x){
    return 0.5f*x*(1.0f + erff(x*0.7071067811865475f));
}

__global__ __launch_bounds__(256) void k_zero(int* __restrict__ p, int n){
    int i = blockIdx.x*256 + threadIdx.x;
    if(i<n) p[i]=0;
}

__global__ __launch_bounds__(256) void k_count(const int* __restrict__ dst, int* __restrict__ cnt){
    int e = blockIdx.x*256 + threadIdx.x;
    if(e<N_EDGES) atomicAdd(&cnt[dst[e]], 1);
}

__global__ __launch_bounds__(256) void k_scan1(const int* __restrict__ cnt, int* __restrict__ rowptr,
                                               int* __restrict__ part){
    __shared__ int sh[256];
    int t=threadIdx.x; int i=blockIdx.x*256+t;
    int v = (i<N_NODES)? cnt[i] : 0;
    sh[t]=v; __syncthreads();
    for(int off=1; off<256; off<<=1){
        int y = (t>=off)? sh[t-off] : 0;
        __syncthreads();
        sh[t] += y;
        __syncthreads();
    }
    if(i<N_NODES) rowptr[i] = sh[t]-v;          // exclusive within chunk
    if(t==255) part[blockIdx.x] = sh[255];      // chunk total
}

__global__ __launch_bounds__(256) void k_scan2(int* __restrict__ part){
    __shared__ int sh[256];
    int t=threadIdx.x;
    int v = (t<SCAN_NB)? part[t] : 0;
    sh[t]=v; __syncthreads();
    for(int off=1; off<256; off<<=1){
        int y=(t>=off)? sh[t-off]:0;
        __syncthreads();
        sh[t]+=y;
        __syncthreads();
    }
    if(t<SCAN_NB) part[t] = sh[t]-v;            // exclusive block offsets
}

__global__ __launch_bounds__(256) void k_scan3(int* __restrict__ rowptr, const int* __restrict__ part,
                                               int* __restrict__ cur){
    int t=threadIdx.x; int i=blockIdx.x*256+t;
    if(i<N_NODES){
        int v = rowptr[i] + part[blockIdx.x];
        rowptr[i]=v; cur[i]=v;
    }
    if(i==0) rowptr[N_NODES]=N_EDGES;
}

__global__ __launch_bounds__(256) void k_fill(const int* __restrict__ src, const int* __restrict__ dst,
                                              int* __restrict__ cur, int* __restrict__ col){
    int e = blockIdx.x*256+threadIdx.x;
    if(e<N_EDGES){
        int d = dst[e];
        int p = atomicAdd(&cur[d],1);
        col[p] = src[e];
    }
}

// h[N,32] = gelu(x[N,128] @ Win[128,32] + bin)   (all fp32)
__global__ __launch_bounds__(256) void k_gemm_in(const float* __restrict__ x, const float* __restrict__ W,
                                                 const float* __restrict__ b, float* __restrict__ h){
    int id = blockIdx.x*256+threadIdx.x;
    int r = id>>5, c = id&31;
    const float4* x4 = (const float4*)(x + (size_t)r*IN_DIM);
    float acc=0.f;
    #pragma unroll 8
    for(int k=0;k<IN_DIM/4;k++){
        float4 xv = x4[k];
        acc = fmaf(xv.x, W[(4*k  )*HID_C+c], acc);
        acc = fmaf(xv.y, W[(4*k+1)*HID_C+c], acc);
        acc = fmaf(xv.z, W[(4*k+2)*HID_C+c], acc);
        acc = fmaf(xv.w, W[(4*k+3)*HID_C+c], acc);
    }
    h[r*HID_C+c] = gelu_f(acc + b[c]);
}

// out[N,128] = h[N,IC] @ W[IC,128] + bias   (all fp32)
// block = 256 threads = 4 waves, 4 rows per wave, 16 rows per block
template<int IC>
__global__ __launch_bounds__(256) void k_gemm(const float* __restrict__ h, const float* __restrict__ W,
                                              const float* __restrict__ bias, float* __restrict__ out){
    __shared__ float hs[4][IC][4];   // [wave][k][row]
    int t=threadIdx.x, wave=t>>6, lane=t&63;
    int rbase = blockIdx.x*16 + wave*4;
    for(int idx=lane; idx<IC*4; idx+=64){
        int k = idx>>2, r = idx&3;
        hs[wave][k][r] = h[(size_t)(rbase+r)*IC + k];
    }
    __syncthreads();
    float ax[4]={0,0,0,0}, ay[4]={0,0,0,0};
    const float2* W2 = (const float2*)W;
    #pragma unroll 4
    for(int k=0;k<IC;k++){
        float2 wv = W2[k*64+lane];
        float4 hv = *(const float4*)&hs[wave][k][0];
        ax[0]=fmaf(hv.x,wv.x,ax[0]); ay[0]=fmaf(hv.x,wv.y,ay[0]);
        ax[1]=fmaf(hv.y,wv.x,ax[1]); ay[1]=fmaf(hv.y,wv.y,ay[1]);
        ax[2]=fmaf(hv.z,wv.x,ax[2]); ay[2]=fmaf(hv.z,wv.y,ay[2]);
        ax[3]=fmaf(hv.w,wv.x,ax[3]); ay[3]=fmaf(hv.w,wv.y,ay[3]);
    }
    float2 bb = ((const float2*)bias)[lane];
    #pragma unroll
    for(int r=0;r<4;r++){
        *(float2*)&out[(size_t)(rbase+r)*HC_DIM + 2*lane] = make_float2(ax[r]+bb.x, ay[r]+bb.y);
    }
}

// fused per-node: online-softmax GATv2 aggregation over CSR in-edges (+ implicit
// self-loop) + bias + LayerNorm + exact GELU + optional residual.
// one wave per node; lane handles channels 2l,2l+1; head = lane/16 (32 ch/head).
__global__ __launch_bounds__(256) void k_node(const float* __restrict__ XL, const float* __restrict__ XR,
    const int* __restrict__ rowptr, const int* __restrict__ colidx,
    const float* __restrict__ att, const float* __restrict__ bo,
    const float* __restrict__ gg, const float* __restrict__ be,
    const float* __restrict__ hold, float* __restrict__ hout)
{
    int wave=threadIdx.x>>6, lane=threadIdx.x&63;
    int node = blockIdx.x*4+wave;
    int c2 = lane<<1;
    float2 xl = *(const float2*)(XL + (size_t)node*HC_DIM + c2);
    float2 av = ((const float2*)att)[lane];
    int beg = rowptr[node], end = rowptr[node+1];
    float m=-1e30f, ls=0.f, a0=0.f, a1=0.f;
    for(int k=beg-1;k<end;k++){
        int j = (k<beg)? node : colidx[k];
        float2 xj = *(const float2*)(XR + (size_t)j*HC_DIM + c2);
        float t0 = xl.x+xj.x; t0 = (t0>0.f)?t0:0.2f*t0;
        float t1 = xl.y+xj.y; t1 = (t1>0.f)?t1:0.2f*t1;
        float part = fmaf(t0,av.x, t1*av.y);
        part += __shfl_xor(part,1);
        part += __shfl_xor(part,2);
        part += __shfl_xor(part,4);
        part += __shfl_xor(part,8);
        float nm = fmaxf(m, part);
        float sc = __expf(m-nm);
        float p  = __expf(part-nm);
        ls = fmaf(ls,sc,p);
        a0 = fmaf(a0,sc, p*xj.x);
        a1 = fmaf(a1,sc, p*xj.y);
        m = nm;
    }
    float inv = 1.0f/ls;
    float2 bov = ((const float2*)bo)[lane];
    float o0 = fmaf(a0,inv,bov.x), o1 = fmaf(a1,inv,bov.y);
    float s1 = o0+o1, s2 = o0*o0+o1*o1;
    #pragma unroll
    for(int msk=1;msk<64;msk<<=1){ s1 += __shfl_xor(s1,msk); s2 += __shfl_xor(s2,msk); }
    float mean = s1*(1.f/128.f);
    float var  = s2*(1.f/128.f) - mean*mean;
    float rstd = rsqrtf(var + 1e-5f);
    float2 gv = ((const float2*)gg)[lane];
    float2 bev= ((const float2*)be)[lane];
    float y0 = fmaf(gv.x*(o0-mean), rstd, bev.x);
    float y1 = fmaf(gv.y*(o1-mean), rstd, bev.y);
    float r0 = gelu_f(y0), r1 = gelu_f(y1);
    if(hold){
        float2 hv = *(const float2*)(hold + (size_t)node*HC_DIM + c2);
        r0 += hv.x; r1 += hv.y;
    }
    *(float2*)(hout + (size_t)node*HC_DIM + c2) = make_float2(r0,r1);
}

// out[N,128] = rownorm(h[N,128] @ W[128,128] + b)   (fp32 out)
__global__ __launch_bounds__(256) void k_outnorm(const float* __restrict__ h, const float* __restrict__ W,
                                                 const float* __restrict__ b, float* __restrict__ out){
    __shared__ float hs[4][HC_DIM][4];
    int t=threadIdx.x, wave=t>>6, lane=t&63;
    int rbase = blockIdx.x*16 + wave*4;
    for(int idx=lane; idx<HC_DIM*4; idx+=64){
        int k=idx>>2, r=idx&3;
        hs[wave][k][r] = h[(size_t)(rbase+r)*HC_DIM + k];
    }
    __syncthreads();
    float ax[4]={0,0,0,0}, ay[4]={0,0,0,0};
    const float2* W2=(const float2*)W;
    #pragma unroll 4
    for(int k=0;k<HC_DIM;k++){
        float2 wv = W2[k*64+lane];
        float4 hv = *(const float4*)&hs[wave][k][0];
        ax[0]=fmaf(hv.x,wv.x,ax[0]); ay[0]=fmaf(hv.x,wv.y,ay[0]);
        ax[1]=fmaf(hv.y,wv.x,ax[1]); ay[1]=fmaf(hv.y,wv.y,ay[1]);
        ax[2]=fmaf(hv.z,wv.x,ax[2]); ay[2]=fmaf(hv.z,wv.y,ay[2]);
        ax[3]=fmaf(hv.w,wv.x,ax[3]); ay[3]=fmaf(hv.w,wv.y,ay[3]);
    }
    float2 bb = ((const float2*)b)[lane];
    #pragma unroll
    for(int r=0;r<4;r++){
        float o0=ax[r]+bb.x, o1=ay[r]+bb.y;
        float ss=o0*o0+o1*o1;
        #pragma unroll
        for(int msk=1;msk<64;msk<<=1) ss += __shfl_xor(ss,msk);
        float invn = 1.0f / fmaxf(sqrtf(ss), 1e-12f);
        *(float2*)&out[(size_t)(rbase+r)*HC_DIM + 2*lane] = make_float2(o0*invn, o1*invn);
    }
}

extern "C" void kernel_launch(void* const* d_in, const int* in_sizes, int n_in,
                              void* d_out, int out_size, void* d_ws, size_t ws_size,
                              hipStream_t stream)
{
    const float* x   = (const float*)d_in[0];
    const int*   ei  = (const int*)  d_in[1];
    const float* Win = (const float*)d_in[2];
    const float* bin = (const float*)d_in[3];
    const float *Wl[3], *bl[3], *Wr[3], *br[3], *att[3], *bo[3], *gg[3], *be[3];
    for(int i=0;i<3;i++){
        const int base = 4 + 8*i;
        Wl[i]=(const float*)d_in[base+0]; bl[i]=(const float*)d_in[base+1];
        Wr[i]=(const float*)d_in[base+2]; br[i]=(const float*)d_in[base+3];
        att[i]=(const float*)d_in[base+4]; bo[i]=(const float*)d_in[base+5];
        gg[i]=(const float*)d_in[base+6]; be[i]=(const float*)d_in[base+7];
    }
    const float* Wout=(const float*)d_in[28];
    const float* bout=(const float*)d_in[29];
    float* out = (float*)d_out;

    char* w = (char*)d_ws;
    float* hA = (float*)w;  w += (size_t)N_NODES*HC_DIM*4;
    float* hB = (float*)w;  w += (size_t)N_NODES*HC_DIM*4;
    float* XL = (float*)w;  w += (size_t)N_NODES*HC_DIM*4;
    float* XR = (float*)w;  w += (size_t)N_NODES*HC_DIM*4;
    int* rowptr = (int*)w;  w += (size_t)(N_NODES+2)*4;
    int* cursor = (int*)w;  w += (size_t)N_NODES*4;
    int* colidx = (int*)w;  w += (size_t)N_EDGES*4;
    int* part   = (int*)w;  w += 256*4;

    const int* srcp = ei;
    const int* dstp = ei + N_EDGES;

    // ---- CSR by destination (built once, reused by all 3 layers) ----
    k_zero  <<<196, 256, 0, stream>>>(cursor, N_NODES);
    k_count <<<3125,256, 0, stream>>>(dstp, cursor);
    k_scan1 <<<SCAN_NB,256,0,stream>>>(cursor, rowptr, part);
    k_scan2 <<<1,   256, 0, stream>>>(part);
    k_scan3 <<<SCAN_NB,256,0,stream>>>(rowptr, part, cursor);
    k_fill  <<<3125,256, 0, stream>>>(srcp, dstp, cursor, colidx);

    // ---- input projection ----
    k_gemm_in<<<6250,256,0,stream>>>(x, Win, bin, hA);

    // ---- layer 0: hA[N,32] -> hB[N,128] (no residual) ----
    k_gemm<32><<<3125,256,0,stream>>>(hA, Wl[0], bl[0], XL);
    k_gemm<32><<<3125,256,0,stream>>>(hA, Wr[0], br[0], XR);
    k_node<<<12500,256,0,stream>>>(XL,XR,rowptr,colidx,att[0],bo[0],gg[0],be[0], (const float*)nullptr, hB);

    // ---- layer 1: hB -> hA (residual hB) ----
    k_gemm<128><<<3125,256,0,stream>>>(hB, Wl[1], bl[1], XL);
    k_gemm<128><<<3125,256,0,stream>>>(hB, Wr[1], br[1], XR);
    k_node<<<12500,256,0,stream>>>(XL,XR,rowptr,colidx,att[1],bo[1],gg[1],be[1], hB, hA);

    // ---- layer 2: hA -> hB (residual hA) ----
    k_gemm<128><<<3125,256,0,stream>>>(hA, Wl[2], bl[2], XL);
    k_gemm<128><<<3125,256,0,stream>>>(hA, Wr[2], br[2], XR);
    k_node<<<12500,256,0,stream>>>(XL,XR,rowptr,colidx,att[2],bo[2],gg[2],be[2], hA, hB);

    // ---- output projection + row L2-normalize ----
    k_outnorm<<<3125,256,0,stream>>>(hB, Wout, bout, out);
}

// Round 3
// 759.341 us; speedup vs baseline: 1.2367x; 1.2367x over previous
//
#include <hip/hip_runtime.h>
#include <hip/hip_bf16.h>
#include <math.h>

#define N_NODES 50000
#define N_EDGES 800000
#define IN_DIM  128
#define HC_DIM  128
#define HID_C   32
#define SCAN_NB 196   // ceil(50000/256)

__device__ __forceinline__ float gelu_f(float x){
    return 0.5f*x*(1.0f + erff(x*0.7071067811865475f));
}

__global__ __launch_bounds__(256) void k_zero(int* __restrict__ p, int n){
    int i = blockIdx.x*256 + threadIdx.x;
    if(i<n) p[i]=0;
}

__global__ __launch_bounds__(256) void k_count(const int* __restrict__ dst, int* __restrict__ cnt){
    int e = blockIdx.x*256 + threadIdx.x;
    if(e<N_EDGES) atomicAdd(&cnt[dst[e]], 1);
}

__global__ __launch_bounds__(256) void k_scan1(const int* __restrict__ cnt, int* __restrict__ rowptr,
                                               int* __restrict__ part){
    __shared__ int sh[256];
    int t=threadIdx.x; int i=blockIdx.x*256+t;
    int v = (i<N_NODES)? cnt[i] : 0;
    sh[t]=v; __syncthreads();
    for(int off=1; off<256; off<<=1){
        int y = (t>=off)? sh[t-off] : 0;
        __syncthreads();
        sh[t] += y;
        __syncthreads();
    }
    if(i<N_NODES) rowptr[i] = sh[t]-v;          // exclusive within chunk
    if(t==255) part[blockIdx.x] = sh[255];      // chunk total
}

__global__ __launch_bounds__(256) void k_scan2(int* __restrict__ part){
    __shared__ int sh[256];
    int t=threadIdx.x;
    int v = (t<SCAN_NB)? part[t] : 0;
    sh[t]=v; __syncthreads();
    for(int off=1; off<256; off<<=1){
        int y=(t>=off)? sh[t-off]:0;
        __syncthreads();
        sh[t]+=y;
        __syncthreads();
    }
    if(t<SCAN_NB) part[t] = sh[t]-v;            // exclusive block offsets
}

__global__ __launch_bounds__(256) void k_scan3(int* __restrict__ rowptr, const int* __restrict__ part,
                                               int* __restrict__ cur){
    int t=threadIdx.x; int i=blockIdx.x*256+t;
    if(i<N_NODES){
        int v = rowptr[i] + part[blockIdx.x];
        rowptr[i]=v; cur[i]=v;
    }
    if(i==0) rowptr[N_NODES]=N_EDGES;
}

__global__ __launch_bounds__(256) void k_fill(const int* __restrict__ src, const int* __restrict__ dst,
                                              int* __restrict__ cur, int* __restrict__ col){
    int e = blockIdx.x*256+threadIdx.x;
    if(e<N_EDGES){
        int d = dst[e];
        int p = atomicAdd(&cur[d],1);
        col[p] = src[e];
    }
}

// h[N,32] = gelu(x[N,128] @ Win[128,32] + bin)   (all fp32)
__global__ __launch_bounds__(256) void k_gemm_in(const float* __restrict__ x, const float* __restrict__ W,
                                                 const float* __restrict__ b, float* __restrict__ h){
    int id = blockIdx.x*256+threadIdx.x;
    int r = id>>5, c = id&31;
    const float4* x4 = (const float4*)(x + (size_t)r*IN_DIM);
    float acc=0.f;
    #pragma unroll 8
    for(int k=0;k<IN_DIM/4;k++){
        float4 xv = x4[k];
        acc = fmaf(xv.x, W[(4*k  )*HID_C+c], acc);
        acc = fmaf(xv.y, W[(4*k+1)*HID_C+c], acc);
        acc = fmaf(xv.z, W[(4*k+2)*HID_C+c], acc);
        acc = fmaf(xv.w, W[(4*k+3)*HID_C+c], acc);
    }
    h[r*HID_C+c] = gelu_f(acc + b[c]);
}

// Fused pair-GEMM: XL = h@Wl + bl, XR = h@Wr + br  (one LDS staging of h serves both)
// block = 256 threads = 4 waves, 4 rows per wave, 16 rows per block
template<int IC>
__global__ __launch_bounds__(256) void k_gemm2(const float* __restrict__ h,
                                               const float* __restrict__ Wl, const float* __restrict__ bl,
                                               const float* __restrict__ Wr, const float* __restrict__ br,
                                               float* __restrict__ XL, float* __restrict__ XR){
    __shared__ float hs[4][IC][4];   // [wave][k][row]
    int t=threadIdx.x, wave=t>>6, lane=t&63;
    int rbase = blockIdx.x*16 + wave*4;
    for(int idx=lane; idx<IC*4; idx+=64){
        int k = idx>>2, r = idx&3;
        hs[wave][k][r] = h[(size_t)(rbase+r)*IC + k];
    }
    __syncthreads();
    float lx[4]={0,0,0,0}, ly[4]={0,0,0,0};
    float rx[4]={0,0,0,0}, ry[4]={0,0,0,0};
    const float2* Wl2 = (const float2*)Wl;
    const float2* Wr2 = (const float2*)Wr;
    #pragma unroll 4
    for(int k=0;k<IC;k++){
        float2 wl = Wl2[k*64+lane];
        float2 wr = Wr2[k*64+lane];
        float4 hv = *(const float4*)&hs[wave][k][0];
        lx[0]=fmaf(hv.x,wl.x,lx[0]); ly[0]=fmaf(hv.x,wl.y,ly[0]);
        lx[1]=fmaf(hv.y,wl.x,lx[1]); ly[1]=fmaf(hv.y,wl.y,ly[1]);
        lx[2]=fmaf(hv.z,wl.x,lx[2]); ly[2]=fmaf(hv.z,wl.y,ly[2]);
        lx[3]=fmaf(hv.w,wl.x,lx[3]); ly[3]=fmaf(hv.w,wl.y,ly[3]);
        rx[0]=fmaf(hv.x,wr.x,rx[0]); ry[0]=fmaf(hv.x,wr.y,ry[0]);
        rx[1]=fmaf(hv.y,wr.x,rx[1]); ry[1]=fmaf(hv.y,wr.y,ry[1]);
        rx[2]=fmaf(hv.z,wr.x,rx[2]); ry[2]=fmaf(hv.z,wr.y,ry[2]);
        rx[3]=fmaf(hv.w,wr.x,rx[3]); ry[3]=fmaf(hv.w,wr.y,ry[3]);
    }
    float2 bbl = ((const float2*)bl)[lane];
    float2 bbr = ((const float2*)br)[lane];
    #pragma unroll
    for(int r=0;r<4;r++){
        *(float2*)&XL[(size_t)(rbase+r)*HC_DIM + 2*lane] = make_float2(lx[r]+bbl.x, ly[r]+bbl.y);
        *(float2*)&XR[(size_t)(rbase+r)*HC_DIM + 2*lane] = make_float2(rx[r]+bbr.x, ry[r]+bbr.y);
    }
}

// fused per-node: online-softmax GATv2 aggregation over CSR in-edges (+ self-loop)
// + bias + LayerNorm + exact GELU + optional residual.
// one wave per node; lane handles channels 2l,2l+1; head = lane/16 (32 ch/head).
// Edge loop unrolled x4: 4 gathers in flight, 4 interleaved shfl chains,
// batched online-softmax update (MLP is the lever — kernel is gather-latency-bound).
__global__ __launch_bounds__(256) void k_node(const float* __restrict__ XL, const float* __restrict__ XR,
    const int* __restrict__ rowptr, const int* __restrict__ colidx,
    const float* __restrict__ att, const float* __restrict__ bo,
    const float* __restrict__ gg, const float* __restrict__ be,
    const float* __restrict__ hold, float* __restrict__ hout)
{
    int wave=threadIdx.x>>6, lane=threadIdx.x&63;
    int node = blockIdx.x*4+wave;
    int c2 = lane<<1;
    float2 xl = *(const float2*)(XL + (size_t)node*HC_DIM + c2);
    float2 av = ((const float2*)att)[lane];
    int beg = rowptr[node], end = rowptr[node+1];

    // self-loop edge (j = node) seeds the online softmax
    float2 xs = *(const float2*)(XR + (size_t)node*HC_DIM + c2);
    float t0 = xl.x+xs.x; t0 = (t0>0.f)?t0:0.2f*t0;
    float t1 = xl.y+xs.y; t1 = (t1>0.f)?t1:0.2f*t1;
    float q  = fmaf(t0,av.x, t1*av.y);
    #pragma unroll
    for(int msk=1;msk<16;msk<<=1) q += __shfl_xor(q,msk);
    float m = q, ls = 1.f, a0 = xs.x, a1 = xs.y;

    int k = beg;
    for(; k+4 <= end; k += 4){
        int j0=colidx[k], j1=colidx[k+1], j2=colidx[k+2], j3=colidx[k+3];
        float2 x0 = *(const float2*)(XR + (size_t)j0*HC_DIM + c2);
        float2 x1 = *(const float2*)(XR + (size_t)j1*HC_DIM + c2);
        float2 x2 = *(const float2*)(XR + (size_t)j2*HC_DIM + c2);
        float2 x3 = *(const float2*)(XR + (size_t)j3*HC_DIM + c2);
        float u0,u1;
        u0 = xl.x+x0.x; u0=(u0>0.f)?u0:0.2f*u0;
        u1 = xl.y+x0.y; u1=(u1>0.f)?u1:0.2f*u1;
        float q0 = fmaf(u0,av.x, u1*av.y);
        u0 = xl.x+x1.x; u0=(u0>0.f)?u0:0.2f*u0;
        u1 = xl.y+x1.y; u1=(u1>0.f)?u1:0.2f*u1;
        float q1 = fmaf(u0,av.x, u1*av.y);
        u0 = xl.x+x2.x; u0=(u0>0.f)?u0:0.2f*u0;
        u1 = xl.y+x2.y; u1=(u1>0.f)?u1:0.2f*u1;
        float q2 = fmaf(u0,av.x, u1*av.y);
        u0 = xl.x+x3.x; u0=(u0>0.f)?u0:0.2f*u0;
        u1 = xl.y+x3.y; u1=(u1>0.f)?u1:0.2f*u1;
        float q3 = fmaf(u0,av.x, u1*av.y);
        #pragma unroll
        for(int msk=1;msk<16;msk<<=1){
            q0 += __shfl_xor(q0,msk);
            q1 += __shfl_xor(q1,msk);
            q2 += __shfl_xor(q2,msk);
            q3 += __shfl_xor(q3,msk);
        }
        float nm = fmaxf(fmaxf(fmaxf(m,q0),fmaxf(q1,q2)),q3);
        float sc = __expf(m-nm);
        float e0 = __expf(q0-nm), e1 = __expf(q1-nm);
        float e2 = __expf(q2-nm), e3 = __expf(q3-nm);
        ls = fmaf(ls,sc, (e0+e1)+(e2+e3));
        a0 = fmaf(a0,sc, fmaf(e0,x0.x, fmaf(e1,x1.x, fmaf(e2,x2.x, e3*x3.x))));
        a1 = fmaf(a1,sc, fmaf(e0,x0.y, fmaf(e1,x1.y, fmaf(e2,x2.y, e3*x3.y))));
        m = nm;
    }
    for(; k<end; k++){
        int j = colidx[k];
        float2 xj = *(const float2*)(XR + (size_t)j*HC_DIM + c2);
        float u0 = xl.x+xj.x; u0=(u0>0.f)?u0:0.2f*u0;
        float u1 = xl.y+xj.y; u1=(u1>0.f)?u1:0.2f*u1;
        float qq = fmaf(u0,av.x, u1*av.y);
        #pragma unroll
        for(int msk=1;msk<16;msk<<=1) qq += __shfl_xor(qq,msk);
        float nm = fmaxf(m, qq);
        float sc = __expf(m-nm);
        float p  = __expf(qq-nm);
        ls = fmaf(ls,sc,p);
        a0 = fmaf(a0,sc, p*xj.x);
        a1 = fmaf(a1,sc, p*xj.y);
        m = nm;
    }

    float inv = 1.0f/ls;
    float2 bov = ((const float2*)bo)[lane];
    float o0 = fmaf(a0,inv,bov.x), o1 = fmaf(a1,inv,bov.y);
    float s1 = o0+o1, s2 = o0*o0+o1*o1;
    #pragma unroll
    for(int msk=1;msk<64;msk<<=1){ s1 += __shfl_xor(s1,msk); s2 += __shfl_xor(s2,msk); }
    float mean = s1*(1.f/128.f);
    float var  = s2*(1.f/128.f) - mean*mean;
    float rstd = rsqrtf(var + 1e-5f);
    float2 gv = ((const float2*)gg)[lane];
    float2 bev= ((const float2*)be)[lane];
    float y0 = fmaf(gv.x*(o0-mean), rstd, bev.x);
    float y1 = fmaf(gv.y*(o1-mean), rstd, bev.y);
    float r0 = gelu_f(y0), r1 = gelu_f(y1);
    if(hold){
        float2 hv = *(const float2*)(hold + (size_t)node*HC_DIM + c2);
        r0 += hv.x; r1 += hv.y;
    }
    *(float2*)(hout + (size_t)node*HC_DIM + c2) = make_float2(r0,r1);
}

// out[N,128] = rownorm(h[N,128] @ W[128,128] + b)   (fp32 out)
__global__ __launch_bounds__(256) void k_outnorm(const float* __restrict__ h, const float* __restrict__ W,
                                                 const float* __restrict__ b, float* __restrict__ out){
    __shared__ float hs[4][HC_DIM][4];
    int t=threadIdx.x, wave=t>>6, lane=t&63;
    int rbase = blockIdx.x*16 + wave*4;
    for(int idx=lane; idx<HC_DIM*4; idx+=64){
        int k=idx>>2, r=idx&3;
        hs[wave][k][r] = h[(size_t)(rbase+r)*HC_DIM + k];
    }
    __syncthreads();
    float ax[4]={0,0,0,0}, ay[4]={0,0,0,0};
    const float2* W2=(const float2*)W;
    #pragma unroll 4
    for(int k=0;k<HC_DIM;k++){
        float2 wv = W2[k*64+lane];
        float4 hv = *(const float4*)&hs[wave][k][0];
        ax[0]=fmaf(hv.x,wv.x,ax[0]); ay[0]=fmaf(hv.x,wv.y,ay[0]);
        ax[1]=fmaf(hv.y,wv.x,ax[1]); ay[1]=fmaf(hv.y,wv.y,ay[1]);
        ax[2]=fmaf(hv.z,wv.x,ax[2]); ay[2]=fmaf(hv.z,wv.y,ay[2]);
        ax[3]=fmaf(hv.w,wv.x,ax[3]); ay[3]=fmaf(hv.w,wv.y,ay[3]);
    }
    float2 bb = ((const float2*)b)[lane];
    #pragma unroll
    for(int r=0;r<4;r++){
        float o0=ax[r]+bb.x, o1=ay[r]+bb.y;
        float ss=o0*o0+o1*o1;
        #pragma unroll
        for(int msk=1;msk<64;msk<<=1) ss += __shfl_xor(ss,msk);
        float invn = 1.0f / fmaxf(sqrtf(ss), 1e-12f);
        *(float2*)&out[(size_t)(rbase+r)*HC_DIM + 2*lane] = make_float2(o0*invn, o1*invn);
    }
}

extern "C" void kernel_launch(void* const* d_in, const int* in_sizes, int n_in,
                              void* d_out, int out_size, void* d_ws, size_t ws_size,
                              hipStream_t stream)
{
    const float* x   = (const float*)d_in[0];
    const int*   ei  = (const int*)  d_in[1];
    const float* Win = (const float*)d_in[2];
    const float* bin = (const float*)d_in[3];
    const float *Wl[3], *bl[3], *Wr[3], *br[3], *att[3], *bo[3], *gg[3], *be[3];
    for(int i=0;i<3;i++){
        const int base = 4 + 8*i;
        Wl[i]=(const float*)d_in[base+0]; bl[i]=(const float*)d_in[base+1];
        Wr[i]=(const float*)d_in[base+2]; br[i]=(const float*)d_in[base+3];
        att[i]=(const float*)d_in[base+4]; bo[i]=(const float*)d_in[base+5];
        gg[i]=(const float*)d_in[base+6]; be[i]=(const float*)d_in[base+7];
    }
    const float* Wout=(const float*)d_in[28];
    const float* bout=(const float*)d_in[29];
    float* out = (float*)d_out;

    char* w = (char*)d_ws;
    float* hA = (float*)w;  w += (size_t)N_NODES*HC_DIM*4;
    float* hB = (float*)w;  w += (size_t)N_NODES*HC_DIM*4;
    float* XL = (float*)w;  w += (size_t)N_NODES*HC_DIM*4;
    float* XR = (float*)w;  w += (size_t)N_NODES*HC_DIM*4;
    int* rowptr = (int*)w;  w += (size_t)(N_NODES+2)*4;
    int* cursor = (int*)w;  w += (size_t)N_NODES*4;
    int* colidx = (int*)w;  w += (size_t)N_EDGES*4;
    int* part   = (int*)w;  w += 256*4;

    const int* srcp = ei;
    const int* dstp = ei + N_EDGES;

    // ---- CSR by destination (built once, reused by all 3 layers) ----
    k_zero  <<<196, 256, 0, stream>>>(cursor, N_NODES);
    k_count <<<3125,256, 0, stream>>>(dstp, cursor);
    k_scan1 <<<SCAN_NB,256,0,stream>>>(cursor, rowptr, part);
    k_scan2 <<<1,   256, 0, stream>>>(part);
    k_scan3 <<<SCAN_NB,256,0,stream>>>(rowptr, part, cursor);
    k_fill  <<<3125,256, 0, stream>>>(srcp, dstp, cursor, colidx);

    // ---- input projection ----
    k_gemm_in<<<6250,256,0,stream>>>(x, Win, bin, hA);

    // ---- layer 0: hA[N,32] -> hB[N,128] (no residual) ----
    k_gemm2<32><<<3125,256,0,stream>>>(hA, Wl[0], bl[0], Wr[0], br[0], XL, XR);
    k_node<<<12500,256,0,stream>>>(XL,XR,rowptr,colidx,att[0],bo[0],gg[0],be[0], (const float*)nullptr, hB);

    // ---- layer 1: hB -> hA (residual hB) ----
    k_gemm2<128><<<3125,256,0,stream>>>(hB, Wl[1], bl[1], Wr[1], br[1], XL, XR);
    k_node<<<12500,256,0,stream>>>(XL,XR,rowptr,colidx,att[1],bo[1],gg[1],be[1], hB, hA);

    // ---- layer 2: hA -> hB (residual hA) ----
    k_gemm2<128><<<3125,256,0,stream>>>(hA, Wl[2], bl[2], Wr[2], br[2], XL, XR);
    k_node<<<12500,256,0,stream>>>(XL,XR,rowptr,colidx,att[2],bo[2],gg[2],be[2], hA, hB);

    // ---- output projection + row L2-normalize ----
    k_outnorm<<<3125,256,0,stream>>>(hB, Wout, bout, out);
}

// Round 4
// 652.545 us; speedup vs baseline: 1.4391x; 1.1637x over previous
//
#include <hip/hip_runtime.h>
#include <hip/hip_bf16.h>
#include <math.h>

#define N_NODES 50000
#define N_EDGES 800000
#define IN_DIM  128
#define HC_DIM  128
#define HID_C   32
#define SCAN_NB 196   // ceil(50000/256)

__device__ __forceinline__ float gelu_f(float x){
    return 0.5f*x*(1.0f + erff(x*0.7071067811865475f));
}

__global__ __launch_bounds__(256) void k_zero(int* __restrict__ p, int n){
    int i = blockIdx.x*256 + threadIdx.x;
    if(i<n) p[i]=0;
}

__global__ __launch_bounds__(256) void k_count(const int* __restrict__ dst, int* __restrict__ cnt){
    int e = blockIdx.x*256 + threadIdx.x;
    if(e<N_EDGES) atomicAdd(&cnt[dst[e]], 1);
}

__global__ __launch_bounds__(256) void k_scan1(const int* __restrict__ cnt, int* __restrict__ rowptr,
                                               int* __restrict__ part){
    __shared__ int sh[256];
    int t=threadIdx.x; int i=blockIdx.x*256+t;
    int v = (i<N_NODES)? cnt[i] : 0;
    sh[t]=v; __syncthreads();
    for(int off=1; off<256; off<<=1){
        int y = (t>=off)? sh[t-off] : 0;
        __syncthreads();
        sh[t] += y;
        __syncthreads();
    }
    if(i<N_NODES) rowptr[i] = sh[t]-v;          // exclusive within chunk
    if(t==255) part[blockIdx.x] = sh[255];      // chunk total
}

__global__ __launch_bounds__(256) void k_scan2(int* __restrict__ part){
    __shared__ int sh[256];
    int t=threadIdx.x;
    int v = (t<SCAN_NB)? part[t] : 0;
    sh[t]=v; __syncthreads();
    for(int off=1; off<256; off<<=1){
        int y=(t>=off)? sh[t-off]:0;
        __syncthreads();
        sh[t]+=y;
        __syncthreads();
    }
    if(t<SCAN_NB) part[t] = sh[t]-v;            // exclusive block offsets
}

__global__ __launch_bounds__(256) void k_scan3(int* __restrict__ rowptr, const int* __restrict__ part,
                                               int* __restrict__ cur){
    int t=threadIdx.x; int i=blockIdx.x*256+t;
    if(i<N_NODES){
        int v = rowptr[i] + part[blockIdx.x];
        rowptr[i]=v; cur[i]=v;
    }
    if(i==0) rowptr[N_NODES]=N_EDGES;
}

__global__ __launch_bounds__(256) void k_fill(const int* __restrict__ src, const int* __restrict__ dst,
                                              int* __restrict__ cur, int* __restrict__ col){
    int e = blockIdx.x*256+threadIdx.x;
    if(e<N_EDGES){
        int d = dst[e];
        int p = atomicAdd(&cur[d],1);
        col[p] = src[e];
    }
}

// h[N,32] = gelu(x[N,128] @ Win[128,32] + bin)   (all fp32)
__global__ __launch_bounds__(256) void k_gemm_in(const float* __restrict__ x, const float* __restrict__ W,
                                                 const float* __restrict__ b, float* __restrict__ h){
    int id = blockIdx.x*256+threadIdx.x;
    int r = id>>5, c = id&31;
    const float4* x4 = (const float4*)(x + (size_t)r*IN_DIM);
    float acc=0.f;
    #pragma unroll 8
    for(int k=0;k<IN_DIM/4;k++){
        float4 xv = x4[k];
        acc = fmaf(xv.x, W[(4*k  )*HID_C+c], acc);
        acc = fmaf(xv.y, W[(4*k+1)*HID_C+c], acc);
        acc = fmaf(xv.z, W[(4*k+2)*HID_C+c], acc);
        acc = fmaf(xv.w, W[(4*k+3)*HID_C+c], acc);
    }
    h[r*HID_C+c] = gelu_f(acc + b[c]);
}

// Register-tiled GEMM: C[M,128] strip = A[M,K] @ W[K,128] + bias, strip of 64 cols.
// 64x64 block tile, 256 threads (tx 0..15 = 4 cols each, ty 0..15 = rows ty+16i),
// 4x4 acc/thread. A row-major LDS (stride K+4: 16B-aligned rows, 2-way banks).
// B staged in two K/2 halves to keep LDS ~50KB -> 3 blocks/CU.
template<int K>
__global__ __launch_bounds__(256) void k_tgemm(const float* __restrict__ A, const float* __restrict__ W,
                                               const float* __restrict__ bias, float* __restrict__ C){
    constexpr int LDA = K + 4;
    constexpr int KH  = K / 2;
    constexpr int NF4 = K / 16;       // per-thread float4 count for A staging
    constexpr int NB4 = K / 32;       // per-thread float4 count for B half-staging
    __shared__ float As[64*LDA];
    __shared__ float Bs[KH*64];
    int t = threadIdx.x;
    int tx = t & 15, ty = t >> 4;
    int rbase = blockIdx.x * 64;
    int cbase = blockIdx.y * 64;

    #pragma unroll
    for(int i=0;i<NF4;i++){
        int idx = t + i*256;
        int row = idx / (K/4);
        int c4  = idx % (K/4);
        int gr = rbase + row; if(gr >= N_NODES) gr = N_NODES-1;
        float4 v = *(const float4*)(A + (size_t)gr*K + c4*4);
        *(float4*)(As + row*LDA + c4*4) = v;
    }

    float acc[4][4];
    #pragma unroll
    for(int i=0;i<4;i++)
        #pragma unroll
        for(int c=0;c<4;c++) acc[i][c]=0.f;

    #pragma unroll
    for(int half=0; half<2; half++){
        if(half) __syncthreads();
        #pragma unroll
        for(int i=0;i<NB4;i++){
            int idx = t + i*256;
            int kl = idx / 16;
            int g  = idx % 16;
            float4 v = *(const float4*)(W + (size_t)(half*KH + kl)*HC_DIM + cbase + g*4);
            *(float4*)(Bs + kl*64 + g*4) = v;
        }
        __syncthreads();
        #pragma unroll 2
        for(int k=0;k<KH;k+=4){
            float4 a0 = *(const float4*)(As + (ty     )*LDA + half*KH + k);
            float4 a1 = *(const float4*)(As + (ty+16)*LDA + half*KH + k);
            float4 a2 = *(const float4*)(As + (ty+32)*LDA + half*KH + k);
            float4 a3 = *(const float4*)(As + (ty+48)*LDA + half*KH + k);
            float4 b0 = *(const float4*)(Bs + (k  )*64 + tx*4);
            float4 b1 = *(const float4*)(Bs + (k+1)*64 + tx*4);
            float4 b2 = *(const float4*)(Bs + (k+2)*64 + tx*4);
            float4 b3 = *(const float4*)(Bs + (k+3)*64 + tx*4);
            #define FMA_STEP(ai, i) \
                acc[i][0]=fmaf(ai.x,b0.x,acc[i][0]); acc[i][1]=fmaf(ai.x,b0.y,acc[i][1]); \
                acc[i][2]=fmaf(ai.x,b0.z,acc[i][2]); acc[i][3]=fmaf(ai.x,b0.w,acc[i][3]); \
                acc[i][0]=fmaf(ai.y,b1.x,acc[i][0]); acc[i][1]=fmaf(ai.y,b1.y,acc[i][1]); \
                acc[i][2]=fmaf(ai.y,b1.z,acc[i][2]); acc[i][3]=fmaf(ai.y,b1.w,acc[i][3]); \
                acc[i][0]=fmaf(ai.z,b2.x,acc[i][0]); acc[i][1]=fmaf(ai.z,b2.y,acc[i][1]); \
                acc[i][2]=fmaf(ai.z,b2.z,acc[i][2]); acc[i][3]=fmaf(ai.z,b2.w,acc[i][3]); \
                acc[i][0]=fmaf(ai.w,b3.x,acc[i][0]); acc[i][1]=fmaf(ai.w,b3.y,acc[i][1]); \
                acc[i][2]=fmaf(ai.w,b3.z,acc[i][2]); acc[i][3]=fmaf(ai.w,b3.w,acc[i][3]);
            FMA_STEP(a0,0) FMA_STEP(a1,1) FMA_STEP(a2,2) FMA_STEP(a3,3)
            #undef FMA_STEP
        }
    }

    float4 bb = *(const float4*)(bias + cbase + tx*4);
    #pragma unroll
    for(int i=0;i<4;i++){
        int gr = rbase + ty + 16*i;
        if(gr < N_NODES){
            float4 o = make_float4(acc[i][0]+bb.x, acc[i][1]+bb.y, acc[i][2]+bb.z, acc[i][3]+bb.w);
            *(float4*)(C + (size_t)gr*HC_DIM + cbase + tx*4) = o;
        }
    }
}

// row L2-normalize: out[r] = tmp[r]/max(||tmp[r]||,1e-12). one wave per row.
__global__ __launch_bounds__(256) void k_rownorm(const float* __restrict__ tmp, float* __restrict__ out){
    int wave=threadIdx.x>>6, lane=threadIdx.x&63;
    int node = blockIdx.x*4+wave;
    float2 v = *(const float2*)(tmp + (size_t)node*HC_DIM + 2*lane);
    float ss = v.x*v.x + v.y*v.y;
    #pragma unroll
    for(int msk=1;msk<64;msk<<=1) ss += __shfl_xor(ss,msk);
    float inv = 1.0f / fmaxf(sqrtf(ss), 1e-12f);
    *(float2*)(out + (size_t)node*HC_DIM + 2*lane) = make_float2(v.x*inv, v.y*inv);
}

// fused per-node: online-softmax GATv2 aggregation over CSR in-edges (+ self-loop)
// + bias + LayerNorm + exact GELU + optional residual.
// one wave per node; lane handles channels 2l,2l+1; head = lane/16 (32 ch/head).
// Edge loop unrolled x8 (8 gathers in flight), x4 mid-tail, scalar tail.
__global__ __launch_bounds__(256) void k_node(const float* __restrict__ XL, const float* __restrict__ XR,
    const int* __restrict__ rowptr, const int* __restrict__ colidx,
    const float* __restrict__ att, const float* __restrict__ bo,
    const float* __restrict__ gg, const float* __restrict__ be,
    const float* __restrict__ hold, float* __restrict__ hout)
{
    int wave=threadIdx.x>>6, lane=threadIdx.x&63;
    int node = blockIdx.x*4+wave;
    int c2 = lane<<1;
    float2 xl = *(const float2*)(XL + (size_t)node*HC_DIM + c2);
    float2 av = ((const float2*)att)[lane];
    int beg = rowptr[node], end = rowptr[node+1];

    // self-loop edge (j = node) seeds the online softmax
    float2 xs = *(const float2*)(XR + (size_t)node*HC_DIM + c2);
    float t0 = xl.x+xs.x; t0 = (t0>0.f)?t0:0.2f*t0;
    float t1 = xl.y+xs.y; t1 = (t1>0.f)?t1:0.2f*t1;
    float q  = fmaf(t0,av.x, t1*av.y);
    #pragma unroll
    for(int msk=1;msk<16;msk<<=1) q += __shfl_xor(q,msk);
    float m = q, ls = 1.f, a0 = xs.x, a1 = xs.y;

    int k = beg;
    for(; k+8 <= end; k += 8){
        int j0=colidx[k],   j1=colidx[k+1], j2=colidx[k+2], j3=colidx[k+3];
        int j4=colidx[k+4], j5=colidx[k+5], j6=colidx[k+6], j7=colidx[k+7];
        float2 x0 = *(const float2*)(XR + (size_t)j0*HC_DIM + c2);
        float2 x1 = *(const float2*)(XR + (size_t)j1*HC_DIM + c2);
        float2 x2 = *(const float2*)(XR + (size_t)j2*HC_DIM + c2);
        float2 x3 = *(const float2*)(XR + (size_t)j3*HC_DIM + c2);
        float2 x4 = *(const float2*)(XR + (size_t)j4*HC_DIM + c2);
        float2 x5 = *(const float2*)(XR + (size_t)j5*HC_DIM + c2);
        float2 x6 = *(const float2*)(XR + (size_t)j6*HC_DIM + c2);
        float2 x7 = *(const float2*)(XR + (size_t)j7*HC_DIM + c2);
        float u0,u1;
        #define LOGIT(xx, qq) \
            u0 = xl.x+xx.x; u0=(u0>0.f)?u0:0.2f*u0; \
            u1 = xl.y+xx.y; u1=(u1>0.f)?u1:0.2f*u1; \
            float qq = fmaf(u0,av.x, u1*av.y);
        LOGIT(x0,q0) LOGIT(x1,q1) LOGIT(x2,q2) LOGIT(x3,q3)
        LOGIT(x4,q4) LOGIT(x5,q5) LOGIT(x6,q6) LOGIT(x7,q7)
        #undef LOGIT
        #pragma unroll
        for(int msk=1;msk<16;msk<<=1){
            q0 += __shfl_xor(q0,msk); q1 += __shfl_xor(q1,msk);
            q2 += __shfl_xor(q2,msk); q3 += __shfl_xor(q3,msk);
            q4 += __shfl_xor(q4,msk); q5 += __shfl_xor(q5,msk);
            q6 += __shfl_xor(q6,msk); q7 += __shfl_xor(q7,msk);
        }
        float nm = fmaxf(m, fmaxf(fmaxf(fmaxf(q0,q1),fmaxf(q2,q3)), fmaxf(fmaxf(q4,q5),fmaxf(q6,q7))));
        float sc = __expf(m-nm);
        float e0=__expf(q0-nm), e1=__expf(q1-nm), e2=__expf(q2-nm), e3=__expf(q3-nm);
        float e4=__expf(q4-nm), e5=__expf(q5-nm), e6=__expf(q6-nm), e7=__expf(q7-nm);
        ls = fmaf(ls,sc, ((e0+e1)+(e2+e3)) + ((e4+e5)+(e6+e7)));
        float s0x = fmaf(e0,x0.x, fmaf(e1,x1.x, fmaf(e2,x2.x, e3*x3.x)));
        float s1x = fmaf(e4,x4.x, fmaf(e5,x5.x, fmaf(e6,x6.x, e7*x7.x)));
        float s0y = fmaf(e0,x0.y, fmaf(e1,x1.y, fmaf(e2,x2.y, e3*x3.y)));
        float s1y = fmaf(e4,x4.y, fmaf(e5,x5.y, fmaf(e6,x6.y, e7*x7.y)));
        a0 = fmaf(a0,sc, s0x+s1x);
        a1 = fmaf(a1,sc, s0y+s1y);
        m = nm;
    }
    if(k+4 <= end){
        int j0=colidx[k], j1=colidx[k+1], j2=colidx[k+2], j3=colidx[k+3];
        float2 x0 = *(const float2*)(XR + (size_t)j0*HC_DIM + c2);
        float2 x1 = *(const float2*)(XR + (size_t)j1*HC_DIM + c2);
        float2 x2 = *(const float2*)(XR + (size_t)j2*HC_DIM + c2);
        float2 x3 = *(const float2*)(XR + (size_t)j3*HC_DIM + c2);
        float u0,u1;
        u0 = xl.x+x0.x; u0=(u0>0.f)?u0:0.2f*u0;
        u1 = xl.y+x0.y; u1=(u1>0.f)?u1:0.2f*u1;
        float q0 = fmaf(u0,av.x, u1*av.y);
        u0 = xl.x+x1.x; u0=(u0>0.f)?u0:0.2f*u0;
        u1 = xl.y+x1.y; u1=(u1>0.f)?u1:0.2f*u1;
        float q1 = fmaf(u0,av.x, u1*av.y);
        u0 = xl.x+x2.x; u0=(u0>0.f)?u0:0.2f*u0;
        u1 = xl.y+x2.y; u1=(u1>0.f)?u1:0.2f*u1;
        float q2 = fmaf(u0,av.x, u1*av.y);
        u0 = xl.x+x3.x; u0=(u0>0.f)?u0:0.2f*u0;
        u1 = xl.y+x3.y; u1=(u1>0.f)?u1:0.2f*u1;
        float q3 = fmaf(u0,av.x, u1*av.y);
        #pragma unroll
        for(int msk=1;msk<16;msk<<=1){
            q0 += __shfl_xor(q0,msk); q1 += __shfl_xor(q1,msk);
            q2 += __shfl_xor(q2,msk); q3 += __shfl_xor(q3,msk);
        }
        float nm = fmaxf(fmaxf(fmaxf(m,q0),fmaxf(q1,q2)),q3);
        float sc = __expf(m-nm);
        float e0 = __expf(q0-nm), e1 = __expf(q1-nm);
        float e2 = __expf(q2-nm), e3 = __expf(q3-nm);
        ls = fmaf(ls,sc, (e0+e1)+(e2+e3));
        a0 = fmaf(a0,sc, fmaf(e0,x0.x, fmaf(e1,x1.x, fmaf(e2,x2.x, e3*x3.x))));
        a1 = fmaf(a1,sc, fmaf(e0,x0.y, fmaf(e1,x1.y, fmaf(e2,x2.y, e3*x3.y))));
        m = nm;
        k += 4;
    }
    for(; k<end; k++){
        int j = colidx[k];
        float2 xj = *(const float2*)(XR + (size_t)j*HC_DIM + c2);
        float u0 = xl.x+xj.x; u0=(u0>0.f)?u0:0.2f*u0;
        float u1 = xl.y+xj.y; u1=(u1>0.f)?u1:0.2f*u1;
        float qq = fmaf(u0,av.x, u1*av.y);
        #pragma unroll
        for(int msk=1;msk<16;msk<<=1) qq += __shfl_xor(qq,msk);
        float nm = fmaxf(m, qq);
        float sc = __expf(m-nm);
        float p  = __expf(qq-nm);
        ls = fmaf(ls,sc,p);
        a0 = fmaf(a0,sc, p*xj.x);
        a1 = fmaf(a1,sc, p*xj.y);
        m = nm;
    }

    float inv = 1.0f/ls;
    float2 bov = ((const float2*)bo)[lane];
    float o0 = fmaf(a0,inv,bov.x), o1 = fmaf(a1,inv,bov.y);
    float s1 = o0+o1, s2 = o0*o0+o1*o1;
    #pragma unroll
    for(int msk=1;msk<64;msk<<=1){ s1 += __shfl_xor(s1,msk); s2 += __shfl_xor(s2,msk); }
    float mean = s1*(1.f/128.f);
    float var  = s2*(1.f/128.f) - mean*mean;
    float rstd = rsqrtf(var + 1e-5f);
    float2 gv = ((const float2*)gg)[lane];
    float2 bev= ((const float2*)be)[lane];
    float y0 = fmaf(gv.x*(o0-mean), rstd, bev.x);
    float y1 = fmaf(gv.y*(o1-mean), rstd, bev.y);
    float r0 = gelu_f(y0), r1 = gelu_f(y1);
    if(hold){
        float2 hv = *(const float2*)(hold + (size_t)node*HC_DIM + c2);
        r0 += hv.x; r1 += hv.y;
    }
    *(float2*)(hout + (size_t)node*HC_DIM + c2) = make_float2(r0,r1);
}

extern "C" void kernel_launch(void* const* d_in, const int* in_sizes, int n_in,
                              void* d_out, int out_size, void* d_ws, size_t ws_size,
                              hipStream_t stream)
{
    const float* x   = (const float*)d_in[0];
    const int*   ei  = (const int*)  d_in[1];
    const float* Win = (const float*)d_in[2];
    const float* bin = (const float*)d_in[3];
    const float *Wl[3], *bl[3], *Wr[3], *br[3], *att[3], *bo[3], *gg[3], *be[3];
    for(int i=0;i<3;i++){
        const int base = 4 + 8*i;
        Wl[i]=(const float*)d_in[base+0]; bl[i]=(const float*)d_in[base+1];
        Wr[i]=(const float*)d_in[base+2]; br[i]=(const float*)d_in[base+3];
        att[i]=(const float*)d_in[base+4]; bo[i]=(const float*)d_in[base+5];
        gg[i]=(const float*)d_in[base+6]; be[i]=(const float*)d_in[base+7];
    }
    const float* Wout=(const float*)d_in[28];
    const float* bout=(const float*)d_in[29];
    float* out = (float*)d_out;

    char* w = (char*)d_ws;
    float* hA = (float*)w;  w += (size_t)N_NODES*HC_DIM*4;
    float* hB = (float*)w;  w += (size_t)N_NODES*HC_DIM*4;
    float* XL = (float*)w;  w += (size_t)N_NODES*HC_DIM*4;
    float* XR = (float*)w;  w += (size_t)N_NODES*HC_DIM*4;
    int* rowptr = (int*)w;  w += (size_t)(N_NODES+2)*4;
    int* cursor = (int*)w;  w += (size_t)N_NODES*4;
    int* colidx = (int*)w;  w += (size_t)N_EDGES*4;
    int* part   = (int*)w;  w += 256*4;

    const int* srcp = ei;
    const int* dstp = ei + N_EDGES;

    const dim3 gemm_grid(782, 2);   // 782 row-tiles x 2 col-strips

    // ---- CSR by destination (built once, reused by all 3 layers) ----
    k_zero  <<<196, 256, 0, stream>>>(cursor, N_NODES);
    k_count <<<3125,256, 0, stream>>>(dstp, cursor);
    k_scan1 <<<SCAN_NB,256,0,stream>>>(cursor, rowptr, part);
    k_scan2 <<<1,   256, 0, stream>>>(part);
    k_scan3 <<<SCAN_NB,256,0,stream>>>(rowptr, part, cursor);
    k_fill  <<<3125,256, 0, stream>>>(srcp, dstp, cursor, colidx);

    // ---- input projection ----
    k_gemm_in<<<6250,256,0,stream>>>(x, Win, bin, hA);

    // ---- layer 0: hA[N,32] -> hB[N,128] (no residual) ----
    k_tgemm<32><<<gemm_grid,256,0,stream>>>(hA, Wl[0], bl[0], XL);
    k_tgemm<32><<<gemm_grid,256,0,stream>>>(hA, Wr[0], br[0], XR);
    k_node<<<12500,256,0,stream>>>(XL,XR,rowptr,colidx,att[0],bo[0],gg[0],be[0], (const float*)nullptr, hB);

    // ---- layer 1: hB -> hA (residual hB) ----
    k_tgemm<128><<<gemm_grid,256,0,stream>>>(hB, Wl[1], bl[1], XL);
    k_tgemm<128><<<gemm_grid,256,0,stream>>>(hB, Wr[1], br[1], XR);
    k_node<<<12500,256,0,stream>>>(XL,XR,rowptr,colidx,att[1],bo[1],gg[1],be[1], hB, hA);

    // ---- layer 2: hA -> hB (residual hA) ----
    k_tgemm<128><<<gemm_grid,256,0,stream>>>(hA, Wl[2], bl[2], XL);
    k_tgemm<128><<<gemm_grid,256,0,stream>>>(hA, Wr[2], br[2], XR);
    k_node<<<12500,256,0,stream>>>(XL,XR,rowptr,colidx,att[2],bo[2],gg[2],be[2], hA, hB);

    // ---- output projection (tiled GEMM -> XL as tmp) + row L2-normalize ----
    k_tgemm<128><<<gemm_grid,256,0,stream>>>(hB, Wout, bout, XL);
    k_rownorm<<<12500,256,0,stream>>>(XL, out);
}

// Round 5
// 627.306 us; speedup vs baseline: 1.4970x; 1.0402x over previous
//
#include <hip/hip_runtime.h>
#include <hip/hip_bf16.h>
#include <math.h>

#define N_NODES 50000
#define N_EDGES 800000
#define IN_DIM  128
#define HC_DIM  128
#define HID_C   32
#define SCAN_NB 196   // ceil(50000/256)

__device__ __forceinline__ float gelu_f(float x){
    return 0.5f*x*(1.0f + erff(x*0.7071067811865475f));
}

__global__ __launch_bounds__(256) void k_zero(int* __restrict__ p, int n){
    int i = blockIdx.x*256 + threadIdx.x;
    if(i<n) p[i]=0;
}

__global__ __launch_bounds__(256) void k_count(const int* __restrict__ dst, int* __restrict__ cnt){
    int e = blockIdx.x*256 + threadIdx.x;
    if(e<N_EDGES) atomicAdd(&cnt[dst[e]], 1);
}

__global__ __launch_bounds__(256) void k_scan1(const int* __restrict__ cnt, int* __restrict__ rowptr,
                                               int* __restrict__ part){
    __shared__ int sh[256];
    int t=threadIdx.x; int i=blockIdx.x*256+t;
    int v = (i<N_NODES)? cnt[i] : 0;
    sh[t]=v; __syncthreads();
    for(int off=1; off<256; off<<=1){
        int y = (t>=off)? sh[t-off] : 0;
        __syncthreads();
        sh[t] += y;
        __syncthreads();
    }
    if(i<N_NODES) rowptr[i] = sh[t]-v;          // exclusive within chunk
    if(t==255) part[blockIdx.x] = sh[255];      // chunk total
}

__global__ __launch_bounds__(256) void k_scan2(int* __restrict__ part){
    __shared__ int sh[256];
    int t=threadIdx.x;
    int v = (t<SCAN_NB)? part[t] : 0;
    sh[t]=v; __syncthreads();
    for(int off=1; off<256; off<<=1){
        int y=(t>=off)? sh[t-off]:0;
        __syncthreads();
        sh[t]+=y;
        __syncthreads();
    }
    if(t<SCAN_NB) part[t] = sh[t]-v;            // exclusive block offsets
}

__global__ __launch_bounds__(256) void k_scan3(int* __restrict__ rowptr, const int* __restrict__ part,
                                               int* __restrict__ cur){
    int t=threadIdx.x; int i=blockIdx.x*256+t;
    if(i<N_NODES){
        int v = rowptr[i] + part[blockIdx.x];
        rowptr[i]=v; cur[i]=v;
    }
    if(i==0) rowptr[N_NODES]=N_EDGES;
}

__global__ __launch_bounds__(256) void k_fill(const int* __restrict__ src, const int* __restrict__ dst,
                                              int* __restrict__ cur, int* __restrict__ col){
    int e = blockIdx.x*256+threadIdx.x;
    if(e<N_EDGES){
        int d = dst[e];
        int p = atomicAdd(&cur[d],1);
        col[p] = src[e];
    }
}

// h[N,32] = gelu(x[N,128] @ Win[128,32] + bin)   (all fp32)
__global__ __launch_bounds__(256) void k_gemm_in(const float* __restrict__ x, const float* __restrict__ W,
                                                 const float* __restrict__ b, float* __restrict__ h){
    int id = blockIdx.x*256+threadIdx.x;
    int r = id>>5, c = id&31;
    const float4* x4 = (const float4*)(x + (size_t)r*IN_DIM);
    float acc=0.f;
    #pragma unroll 8
    for(int k=0;k<IN_DIM/4;k++){
        float4 xv = x4[k];
        acc = fmaf(xv.x, W[(4*k  )*HID_C+c], acc);
        acc = fmaf(xv.y, W[(4*k+1)*HID_C+c], acc);
        acc = fmaf(xv.z, W[(4*k+2)*HID_C+c], acc);
        acc = fmaf(xv.w, W[(4*k+3)*HID_C+c], acc);
    }
    h[r*HID_C+c] = gelu_f(acc + b[c]);
}

// Pair register-tiled GEMM: XL/XR[64-row,64-col strip] = A @ {Wl,Wr} + {bl,br}.
// A staged once in LDS serves both weight matrices (2x arithmetic per staging).
// 256 threads: tx 0..15 = 4 cols each, ty 0..15 = rows ty+16i; 2x4x4 acc/thread.
// B in two K/2 halves: LDS = As 64*(K+4)*4 + 2*(K/2*64*4) -> 66KB @K=128 (2 blk/CU).
template<int K>
__global__ __launch_bounds__(256) void k_tgemm2(const float* __restrict__ A,
                                                const float* __restrict__ Wl, const float* __restrict__ bl,
                                                const float* __restrict__ Wr, const float* __restrict__ br,
                                                float* __restrict__ XL, float* __restrict__ XR){
    constexpr int LDA = K + 4;
    constexpr int KH  = K / 2;
    constexpr int NF4 = K / 16;       // per-thread float4 count for A staging
    constexpr int NB4 = K / 32;       // per-thread float4 count per B half-staging
    __shared__ float As[64*LDA];
    __shared__ float Bsl[KH*64];
    __shared__ float Bsr[KH*64];
    int t = threadIdx.x;
    int tx = t & 15, ty = t >> 4;
    int rbase = blockIdx.x * 64;
    int cbase = blockIdx.y * 64;

    #pragma unroll
    for(int i=0;i<NF4;i++){
        int idx = t + i*256;
        int row = idx / (K/4);
        int c4  = idx % (K/4);
        int gr = rbase + row; if(gr >= N_NODES) gr = N_NODES-1;
        float4 v = *(const float4*)(A + (size_t)gr*K + c4*4);
        *(float4*)(As + row*LDA + c4*4) = v;
    }

    float accL[4][4], accR[4][4];
    #pragma unroll
    for(int i=0;i<4;i++)
        #pragma unroll
        for(int c=0;c<4;c++){ accL[i][c]=0.f; accR[i][c]=0.f; }

    #pragma unroll
    for(int half=0; half<2; half++){
        if(half) __syncthreads();
        #pragma unroll
        for(int i=0;i<NB4;i++){
            int idx = t + i*256;
            int kl = idx / 16;
            int g  = idx % 16;
            *(float4*)(Bsl + kl*64 + g*4) = *(const float4*)(Wl + (size_t)(half*KH + kl)*HC_DIM + cbase + g*4);
            *(float4*)(Bsr + kl*64 + g*4) = *(const float4*)(Wr + (size_t)(half*KH + kl)*HC_DIM + cbase + g*4);
        }
        __syncthreads();
        #pragma unroll 2
        for(int k=0;k<KH;k+=4){
            float4 a0 = *(const float4*)(As + (ty   )*LDA + half*KH + k);
            float4 a1 = *(const float4*)(As + (ty+16)*LDA + half*KH + k);
            float4 a2 = *(const float4*)(As + (ty+32)*LDA + half*KH + k);
            float4 a3 = *(const float4*)(As + (ty+48)*LDA + half*KH + k);
            float4 l0 = *(const float4*)(Bsl + (k  )*64 + tx*4);
            float4 l1 = *(const float4*)(Bsl + (k+1)*64 + tx*4);
            float4 l2 = *(const float4*)(Bsl + (k+2)*64 + tx*4);
            float4 l3 = *(const float4*)(Bsl + (k+3)*64 + tx*4);
            float4 r0 = *(const float4*)(Bsr + (k  )*64 + tx*4);
            float4 r1 = *(const float4*)(Bsr + (k+1)*64 + tx*4);
            float4 r2 = *(const float4*)(Bsr + (k+2)*64 + tx*4);
            float4 r3 = *(const float4*)(Bsr + (k+3)*64 + tx*4);
            #define FMA_STEP(ai, i) \
                accL[i][0]=fmaf(ai.x,l0.x,accL[i][0]); accL[i][1]=fmaf(ai.x,l0.y,accL[i][1]); \
                accL[i][2]=fmaf(ai.x,l0.z,accL[i][2]); accL[i][3]=fmaf(ai.x,l0.w,accL[i][3]); \
                accL[i][0]=fmaf(ai.y,l1.x,accL[i][0]); accL[i][1]=fmaf(ai.y,l1.y,accL[i][1]); \
                accL[i][2]=fmaf(ai.y,l1.z,accL[i][2]); accL[i][3]=fmaf(ai.y,l1.w,accL[i][3]); \
                accL[i][0]=fmaf(ai.z,l2.x,accL[i][0]); accL[i][1]=fmaf(ai.z,l2.y,accL[i][1]); \
                accL[i][2]=fmaf(ai.z,l2.z,accL[i][2]); accL[i][3]=fmaf(ai.z,l2.w,accL[i][3]); \
                accL[i][0]=fmaf(ai.w,l3.x,accL[i][0]); accL[i][1]=fmaf(ai.w,l3.y,accL[i][1]); \
                accL[i][2]=fmaf(ai.w,l3.z,accL[i][2]); accL[i][3]=fmaf(ai.w,l3.w,accL[i][3]); \
                accR[i][0]=fmaf(ai.x,r0.x,accR[i][0]); accR[i][1]=fmaf(ai.x,r0.y,accR[i][1]); \
                accR[i][2]=fmaf(ai.x,r0.z,accR[i][2]); accR[i][3]=fmaf(ai.x,r0.w,accR[i][3]); \
                accR[i][0]=fmaf(ai.y,r1.x,accR[i][0]); accR[i][1]=fmaf(ai.y,r1.y,accR[i][1]); \
                accR[i][2]=fmaf(ai.y,r1.z,accR[i][2]); accR[i][3]=fmaf(ai.y,r1.w,accR[i][3]); \
                accR[i][0]=fmaf(ai.z,r2.x,accR[i][0]); accR[i][1]=fmaf(ai.z,r2.y,accR[i][1]); \
                accR[i][2]=fmaf(ai.z,r2.z,accR[i][2]); accR[i][3]=fmaf(ai.z,r2.w,accR[i][3]); \
                accR[i][0]=fmaf(ai.w,r3.x,accR[i][0]); accR[i][1]=fmaf(ai.w,r3.y,accR[i][1]); \
                accR[i][2]=fmaf(ai.w,r3.z,accR[i][2]); accR[i][3]=fmaf(ai.w,r3.w,accR[i][3]);
            FMA_STEP(a0,0) FMA_STEP(a1,1) FMA_STEP(a2,2) FMA_STEP(a3,3)
            #undef FMA_STEP
        }
    }

    float4 bbl = *(const float4*)(bl + cbase + tx*4);
    float4 bbr = *(const float4*)(br + cbase + tx*4);
    #pragma unroll
    for(int i=0;i<4;i++){
        int gr = rbase + ty + 16*i;
        if(gr < N_NODES){
            *(float4*)(XL + (size_t)gr*HC_DIM + cbase + tx*4) =
                make_float4(accL[i][0]+bbl.x, accL[i][1]+bbl.y, accL[i][2]+bbl.z, accL[i][3]+bbl.w);
            *(float4*)(XR + (size_t)gr*HC_DIM + cbase + tx*4) =
                make_float4(accR[i][0]+bbr.x, accR[i][1]+bbr.y, accR[i][2]+bbr.z, accR[i][3]+bbr.w);
        }
    }
}

// Single register-tiled GEMM (used for output projection).
template<int K>
__global__ __launch_bounds__(256) void k_tgemm(const float* __restrict__ A, const float* __restrict__ W,
                                               const float* __restrict__ bias, float* __restrict__ C){
    constexpr int LDA = K + 4;
    constexpr int KH  = K / 2;
    constexpr int NF4 = K / 16;
    constexpr int NB4 = K / 32;
    __shared__ float As[64*LDA];
    __shared__ float Bs[KH*64];
    int t = threadIdx.x;
    int tx = t & 15, ty = t >> 4;
    int rbase = blockIdx.x * 64;
    int cbase = blockIdx.y * 64;

    #pragma unroll
    for(int i=0;i<NF4;i++){
        int idx = t + i*256;
        int row = idx / (K/4);
        int c4  = idx % (K/4);
        int gr = rbase + row; if(gr >= N_NODES) gr = N_NODES-1;
        float4 v = *(const float4*)(A + (size_t)gr*K + c4*4);
        *(float4*)(As + row*LDA + c4*4) = v;
    }

    float acc[4][4];
    #pragma unroll
    for(int i=0;i<4;i++)
        #pragma unroll
        for(int c=0;c<4;c++) acc[i][c]=0.f;

    #pragma unroll
    for(int half=0; half<2; half++){
        if(half) __syncthreads();
        #pragma unroll
        for(int i=0;i<NB4;i++){
            int idx = t + i*256;
            int kl = idx / 16;
            int g  = idx % 16;
            *(float4*)(Bs + kl*64 + g*4) = *(const float4*)(W + (size_t)(half*KH + kl)*HC_DIM + cbase + g*4);
        }
        __syncthreads();
        #pragma unroll 2
        for(int k=0;k<KH;k+=4){
            float4 a0 = *(const float4*)(As + (ty   )*LDA + half*KH + k);
            float4 a1 = *(const float4*)(As + (ty+16)*LDA + half*KH + k);
            float4 a2 = *(const float4*)(As + (ty+32)*LDA + half*KH + k);
            float4 a3 = *(const float4*)(As + (ty+48)*LDA + half*KH + k);
            float4 b0 = *(const float4*)(Bs + (k  )*64 + tx*4);
            float4 b1 = *(const float4*)(Bs + (k+1)*64 + tx*4);
            float4 b2 = *(const float4*)(Bs + (k+2)*64 + tx*4);
            float4 b3 = *(const float4*)(Bs + (k+3)*64 + tx*4);
            #define FMA_STEP(ai, i) \
                acc[i][0]=fmaf(ai.x,b0.x,acc[i][0]); acc[i][1]=fmaf(ai.x,b0.y,acc[i][1]); \
                acc[i][2]=fmaf(ai.x,b0.z,acc[i][2]); acc[i][3]=fmaf(ai.x,b0.w,acc[i][3]); \
                acc[i][0]=fmaf(ai.y,b1.x,acc[i][0]); acc[i][1]=fmaf(ai.y,b1.y,acc[i][1]); \
                acc[i][2]=fmaf(ai.y,b1.z,acc[i][2]); acc[i][3]=fmaf(ai.y,b1.w,acc[i][3]); \
                acc[i][0]=fmaf(ai.z,b2.x,acc[i][0]); acc[i][1]=fmaf(ai.z,b2.y,acc[i][1]); \
                acc[i][2]=fmaf(ai.z,b2.z,acc[i][2]); acc[i][3]=fmaf(ai.z,b2.w,acc[i][3]); \
                acc[i][0]=fmaf(ai.w,b3.x,acc[i][0]); acc[i][1]=fmaf(ai.w,b3.y,acc[i][1]); \
                acc[i][2]=fmaf(ai.w,b3.z,acc[i][2]); acc[i][3]=fmaf(ai.w,b3.w,acc[i][3]);
            FMA_STEP(a0,0) FMA_STEP(a1,1) FMA_STEP(a2,2) FMA_STEP(a3,3)
            #undef FMA_STEP
        }
    }

    float4 bb = *(const float4*)(bias + cbase + tx*4);
    #pragma unroll
    for(int i=0;i<4;i++){
        int gr = rbase + ty + 16*i;
        if(gr < N_NODES){
            *(float4*)(C + (size_t)gr*HC_DIM + cbase + tx*4) =
                make_float4(acc[i][0]+bb.x, acc[i][1]+bb.y, acc[i][2]+bb.z, acc[i][3]+bb.w);
        }
    }
}

// row L2-normalize: out[r] = tmp[r]/max(||tmp[r]||,1e-12). one wave per row.
__global__ __launch_bounds__(256) void k_rownorm(const float* __restrict__ tmp, float* __restrict__ out){
    int wave=threadIdx.x>>6, lane=threadIdx.x&63;
    int node = blockIdx.x*4+wave;
    float2 v = *(const float2*)(tmp + (size_t)node*HC_DIM + 2*lane);
    float ss = v.x*v.x + v.y*v.y;
    #pragma unroll
    for(int msk=1;msk<64;msk<<=1) ss += __shfl_xor(ss,msk);
    float inv = 1.0f / fmaxf(sqrtf(ss), 1e-12f);
    *(float2*)(out + (size_t)node*HC_DIM + 2*lane) = make_float2(v.x*inv, v.y*inv);
}

// fused per-node GATv2: one wave per node. Lane layout: cg = lane&31 owns channels
// [4cg..4cg+4) (float4), half = lane>>5 owns alternate edges. Head = cg>>3; the
// head-dot reduction is 3 shfls over 8 lanes serving 2 edges per instruction
// (vs 4 shfls/edge at 2ch/lane). Two half-wave online-softmax states merge at end.
__global__ __launch_bounds__(256) void k_node(const float* __restrict__ XL, const float* __restrict__ XR,
    const int* __restrict__ rowptr, const int* __restrict__ colidx,
    const float* __restrict__ att, const float* __restrict__ bo,
    const float* __restrict__ gg, const float* __restrict__ be,
    const float* __restrict__ hold, float* __restrict__ hout)
{
    int wave=threadIdx.x>>6, lane=threadIdx.x&63;
    int node = blockIdx.x*4+wave;
    int cg = lane & 31, half = lane >> 5;
    int c4 = cg << 2;

    float4 xl = *(const float4*)(XL + (size_t)node*HC_DIM + c4);
    float4 av = *(const float4*)(att + c4);
    int beg = rowptr[node], end = rowptr[node+1];

    #define EDGE_LOGIT(xj, q) { \
        float u0 = xl.x + xj.x; u0 = (u0>0.f)?u0:0.2f*u0; \
        float u1 = xl.y + xj.y; u1 = (u1>0.f)?u1:0.2f*u1; \
        float u2 = xl.z + xj.z; u2 = (u2>0.f)?u2:0.2f*u2; \
        float u3 = xl.w + xj.w; u3 = (u3>0.f)?u3:0.2f*u3; \
        q = fmaf(u0,av.x, fmaf(u1,av.y, fmaf(u2,av.z, u3*av.w))); \
        q += __shfl_xor(q,1); q += __shfl_xor(q,2); q += __shfl_xor(q,4); }

    // self-loop seeds half 0; half 1 starts empty
    float4 xs = *(const float4*)(XR + (size_t)node*HC_DIM + c4);
    float qs; EDGE_LOGIT(xs, qs)
    float m, ls; float4 acc;
    if(half==0){ m = qs; ls = 1.f; acc = xs; }
    else       { m = -INFINITY; ls = 0.f; acc = make_float4(0.f,0.f,0.f,0.f); }

    int P = end - beg;
    int nb = P >> 3;
    int base = beg;
    for(int b=0; b<nb; b++, base += 8){
        int j0 = colidx[base     + half];
        int j1 = colidx[base + 2 + half];
        int j2 = colidx[base + 4 + half];
        int j3 = colidx[base + 6 + half];
        float4 x0 = *(const float4*)(XR + (size_t)j0*HC_DIM + c4);
        float4 x1 = *(const float4*)(XR + (size_t)j1*HC_DIM + c4);
        float4 x2 = *(const float4*)(XR + (size_t)j2*HC_DIM + c4);
        float4 x3 = *(const float4*)(XR + (size_t)j3*HC_DIM + c4);
        float q0,q1,q2,q3;
        EDGE_LOGIT(x0,q0) EDGE_LOGIT(x1,q1) EDGE_LOGIT(x2,q2) EDGE_LOGIT(x3,q3)
        float nm = fmaxf(m, fmaxf(fmaxf(q0,q1),fmaxf(q2,q3)));
        float sc = __expf(m-nm);
        float e0 = __expf(q0-nm), e1 = __expf(q1-nm);
        float e2 = __expf(q2-nm), e3 = __expf(q3-nm);
        ls = fmaf(ls, sc, (e0+e1)+(e2+e3));
        acc.x = fmaf(acc.x, sc, fmaf(e0,x0.x, fmaf(e1,x1.x, fmaf(e2,x2.x, e3*x3.x))));
        acc.y = fmaf(acc.y, sc, fmaf(e0,x0.y, fmaf(e1,x1.y, fmaf(e2,x2.y, e3*x3.y))));
        acc.z = fmaf(acc.z, sc, fmaf(e0,x0.z, fmaf(e1,x1.z, fmaf(e2,x2.z, e3*x3.z))));
        acc.w = fmaf(acc.w, sc, fmaf(e0,x0.w, fmaf(e1,x1.w, fmaf(e2,x2.w, e3*x3.w))));
        m = nm;
    }
    // tail: up to 7 edges, alternate halves (idx uniform within each half-wave,
    // so the shfl reduction partners are all active together)
    #pragma unroll
    for(int i=0;i<4;i++){
        int idx = base + 2*i + half;
        if(idx < end){
            int j = colidx[idx];
            float4 xj = *(const float4*)(XR + (size_t)j*HC_DIM + c4);
            float q; EDGE_LOGIT(xj, q)
            float nm = fmaxf(m, q);
            float sc = __expf(m-nm);
            float p  = __expf(q-nm);
            ls = fmaf(ls, sc, p);
            acc.x = fmaf(acc.x, sc, p*xj.x);
            acc.y = fmaf(acc.y, sc, p*xj.y);
            acc.z = fmaf(acc.z, sc, p*xj.z);
            acc.w = fmaf(acc.w, sc, p*xj.w);
            m = nm;
        }
    }
    #undef EDGE_LOGIT

    // merge the two half-wave softmax states
    {
        float mo  = __shfl_xor(m, 32);
        float lso = __shfl_xor(ls, 32);
        float4 ao;
        ao.x = __shfl_xor(acc.x,32); ao.y = __shfl_xor(acc.y,32);
        ao.z = __shfl_xor(acc.z,32); ao.w = __shfl_xor(acc.w,32);
        float nm = fmaxf(m, mo);
        float s0 = __expf(m-nm), s1 = __expf(mo-nm);
        ls = ls*s0 + lso*s1;
        acc.x = acc.x*s0 + ao.x*s1;
        acc.y = acc.y*s0 + ao.y*s1;
        acc.z = acc.z*s0 + ao.z*s1;
        acc.w = acc.w*s0 + ao.w*s1;
    }

    float inv = 1.0f/ls;
    float4 bo4 = *(const float4*)(bo + c4);
    float o0 = fmaf(acc.x,inv,bo4.x), o1 = fmaf(acc.y,inv,bo4.y);
    float o2 = fmaf(acc.z,inv,bo4.z), o3 = fmaf(acc.w,inv,bo4.w);
    float s1v = (o0+o1)+(o2+o3);
    float s2v = fmaf(o0,o0, fmaf(o1,o1, fmaf(o2,o2, o3*o3)));
    #pragma unroll
    for(int msk=1;msk<32;msk<<=1){ s1v += __shfl_xor(s1v,msk); s2v += __shfl_xor(s2v,msk); }
    float mean = s1v*(1.f/128.f);
    float var  = s2v*(1.f/128.f) - mean*mean;
    float rstd = rsqrtf(var + 1e-5f);
    float4 g4  = *(const float4*)(gg + c4);
    float4 be4 = *(const float4*)(be + c4);
    float r0 = gelu_f(fmaf(g4.x*(o0-mean), rstd, be4.x));
    float r1 = gelu_f(fmaf(g4.y*(o1-mean), rstd, be4.y));
    float r2 = gelu_f(fmaf(g4.z*(o2-mean), rstd, be4.z));
    float r3 = gelu_f(fmaf(g4.w*(o3-mean), rstd, be4.w));
    if(hold){
        float4 hv = *(const float4*)(hold + (size_t)node*HC_DIM + c4);
        r0 += hv.x; r1 += hv.y; r2 += hv.z; r3 += hv.w;
    }
    if(half==0)
        *(float4*)(hout + (size_t)node*HC_DIM + c4) = make_float4(r0,r1,r2,r3);
}

extern "C" void kernel_launch(void* const* d_in, const int* in_sizes, int n_in,
                              void* d_out, int out_size, void* d_ws, size_t ws_size,
                              hipStream_t stream)
{
    const float* x   = (const float*)d_in[0];
    const int*   ei  = (const int*)  d_in[1];
    const float* Win = (const float*)d_in[2];
    const float* bin = (const float*)d_in[3];
    const float *Wl[3], *bl[3], *Wr[3], *br[3], *att[3], *bo[3], *gg[3], *be[3];
    for(int i=0;i<3;i++){
        const int base = 4 + 8*i;
        Wl[i]=(const float*)d_in[base+0]; bl[i]=(const float*)d_in[base+1];
        Wr[i]=(const float*)d_in[base+2]; br[i]=(const float*)d_in[base+3];
        att[i]=(const float*)d_in[base+4]; bo[i]=(const float*)d_in[base+5];
        gg[i]=(const float*)d_in[base+6]; be[i]=(const float*)d_in[base+7];
    }
    const float* Wout=(const float*)d_in[28];
    const float* bout=(const float*)d_in[29];
    float* out = (float*)d_out;

    char* w = (char*)d_ws;
    float* hA = (float*)w;  w += (size_t)N_NODES*HC_DIM*4;
    float* hB = (float*)w;  w += (size_t)N_NODES*HC_DIM*4;
    float* XL = (float*)w;  w += (size_t)N_NODES*HC_DIM*4;
    float* XR = (float*)w;  w += (size_t)N_NODES*HC_DIM*4;
    int* rowptr = (int*)w;  w += (size_t)(N_NODES+2)*4;
    int* cursor = (int*)w;  w += (size_t)N_NODES*4;
    int* colidx = (int*)w;  w += (size_t)N_EDGES*4;
    int* part   = (int*)w;  w += 256*4;

    const int* srcp = ei;
    const int* dstp = ei + N_EDGES;

    const dim3 gemm_grid(782, 2);   // 782 row-tiles x 2 col-strips

    // ---- CSR by destination (built once, reused by all 3 layers) ----
    k_zero  <<<196, 256, 0, stream>>>(cursor, N_NODES);
    k_count <<<3125,256, 0, stream>>>(dstp, cursor);
    k_scan1 <<<SCAN_NB,256,0,stream>>>(cursor, rowptr, part);
    k_scan2 <<<1,   256, 0, stream>>>(part);
    k_scan3 <<<SCAN_NB,256,0,stream>>>(rowptr, part, cursor);
    k_fill  <<<3125,256, 0, stream>>>(srcp, dstp, cursor, colidx);

    // ---- input projection ----
    k_gemm_in<<<6250,256,0,stream>>>(x, Win, bin, hA);

    // ---- layer 0: hA[N,32] -> hB[N,128] (no residual) ----
    k_tgemm2<32><<<gemm_grid,256,0,stream>>>(hA, Wl[0], bl[0], Wr[0], br[0], XL, XR);
    k_node<<<12500,256,0,stream>>>(XL,XR,rowptr,colidx,att[0],bo[0],gg[0],be[0], (const float*)nullptr, hB);

    // ---- layer 1: hB -> hA (residual hB) ----
    k_tgemm2<128><<<gemm_grid,256,0,stream>>>(hB, Wl[1], bl[1], Wr[1], br[1], XL, XR);
    k_node<<<12500,256,0,stream>>>(XL,XR,rowptr,colidx,att[1],bo[1],gg[1],be[1], hB, hA);

    // ---- layer 2: hA -> hB (residual hA) ----
    k_tgemm2<128><<<gemm_grid,256,0,stream>>>(hA, Wl[2], bl[2], Wr[2], br[2], XL, XR);
    k_node<<<12500,256,0,stream>>>(XL,XR,rowptr,colidx,att[2],bo[2],gg[2],be[2], hA, hB);

    // ---- output projection (tiled GEMM -> XL as tmp) + row L2-normalize ----
    k_tgemm<128><<<gemm_grid,256,0,stream>>>(hB, Wout, bout, XL);
    k_rownorm<<<12500,256,0,stream>>>(XL, out);
}

// Round 6
// 563.820 us; speedup vs baseline: 1.6656x; 1.1126x over previous
//
#include <hip/hip_runtime.h>
#include <hip/hip_bf16.h>
#include <math.h>

#define N_NODES 50000
#define N_EDGES 800000
#define IN_DIM  128
#define HC_DIM  128
#define HID_C   32
#define SCAN_NB 196   // ceil(50000/256)

typedef __attribute__((ext_vector_type(8))) short short8;   // 8 bf16 = 4 VGPR (MFMA A/B frag)
typedef __attribute__((ext_vector_type(4))) float f32x4;    // MFMA C/D frag

__device__ __forceinline__ float gelu_f(float x){
    return 0.5f*x*(1.0f + erff(x*0.7071067811865475f));
}

// fp32 -> (hi, lo) bf16 split: hi = rn(f), lo = rn(f - hi). hi*hi + hi*lo + lo*hi
// recovers ~fp32 precision in MFMA (lo*lo term ~2^-32, dropped).
__device__ __forceinline__ void split2(float f, short& h, short& l){
    __hip_bfloat16 bh = __float2bfloat16(f);
    float r = f - __bfloat162float(bh);
    __hip_bfloat16 blo = __float2bfloat16(r);
    h = *reinterpret_cast<short*>(&bh);
    l = *reinterpret_cast<short*>(&blo);
}

__global__ __launch_bounds__(256) void k_zero(int* __restrict__ p, int n){
    int i = blockIdx.x*256 + threadIdx.x;
    if(i<n) p[i]=0;
}

__global__ __launch_bounds__(256) void k_count(const int* __restrict__ dst, int* __restrict__ cnt){
    int e = blockIdx.x*256 + threadIdx.x;
    if(e<N_EDGES) atomicAdd(&cnt[dst[e]], 1);
}

__global__ __launch_bounds__(256) void k_scan1(const int* __restrict__ cnt, int* __restrict__ rowptr,
                                               int* __restrict__ part){
    __shared__ int sh[256];
    int t=threadIdx.x; int i=blockIdx.x*256+t;
    int v = (i<N_NODES)? cnt[i] : 0;
    sh[t]=v; __syncthreads();
    for(int off=1; off<256; off<<=1){
        int y = (t>=off)? sh[t-off] : 0;
        __syncthreads();
        sh[t] += y;
        __syncthreads();
    }
    if(i<N_NODES) rowptr[i] = sh[t]-v;          // exclusive within chunk
    if(t==255) part[blockIdx.x] = sh[255];      // chunk total
}

__global__ __launch_bounds__(256) void k_scan2(int* __restrict__ part){
    __shared__ int sh[256];
    int t=threadIdx.x;
    int v = (t<SCAN_NB)? part[t] : 0;
    sh[t]=v; __syncthreads();
    for(int off=1; off<256; off<<=1){
        int y=(t>=off)? sh[t-off]:0;
        __syncthreads();
        sh[t]+=y;
        __syncthreads();
    }
    if(t<SCAN_NB) part[t] = sh[t]-v;            // exclusive block offsets
}

__global__ __launch_bounds__(256) void k_scan3(int* __restrict__ rowptr, const int* __restrict__ part,
                                               int* __restrict__ cur){
    int t=threadIdx.x; int i=blockIdx.x*256+t;
    if(i<N_NODES){
        int v = rowptr[i] + part[blockIdx.x];
        rowptr[i]=v; cur[i]=v;
    }
    if(i==0) rowptr[N_NODES]=N_EDGES;
}

__global__ __launch_bounds__(256) void k_fill(const int* __restrict__ src, const int* __restrict__ dst,
                                              int* __restrict__ cur, int* __restrict__ col){
    int e = blockIdx.x*256+threadIdx.x;
    if(e<N_EDGES){
        int d = dst[e];
        int p = atomicAdd(&cur[d],1);
        col[p] = src[e];
    }
}

// h[N,32] = gelu(x[N,128] @ Win[128,32] + bin)   (all fp32)
__global__ __launch_bounds__(256) void k_gemm_in(const float* __restrict__ x, const float* __restrict__ W,
                                                 const float* __restrict__ b, float* __restrict__ h){
    int id = blockIdx.x*256+threadIdx.x;
    int r = id>>5, c = id&31;
    const float4* x4 = (const float4*)(x + (size_t)r*IN_DIM);
    float acc=0.f;
    #pragma unroll 8
    for(int k=0;k<IN_DIM/4;k++){
        float4 xv = x4[k];
        acc = fmaf(xv.x, W[(4*k  )*HID_C+c], acc);
        acc = fmaf(xv.y, W[(4*k+1)*HID_C+c], acc);
        acc = fmaf(xv.z, W[(4*k+2)*HID_C+c], acc);
        acc = fmaf(xv.w, W[(4*k+3)*HID_C+c], acc);
    }
    h[r*HID_C+c] = gelu_f(acc + b[c]);
}

// MFMA GEMM (bf16x3 split, ~fp32 precision): C[64-rows x 64-col strip] = A@W + bias.
// PAIR=true computes XL = A@Wl+bl and XR = A@Wr+br with one A staging.
// Block: 256 thr = 4 waves; wave w owns n-subtile [w*16, w*16+16); 4 m-tiles of 16.
// Per K-chunk (KC=32): A (64x32 fp32) and W (32x64 fp32) are read from global,
// split to hi/lo bf16 in LDS (W transposed to [n][k] so the B-frag read
// B[k][n], n=lane&15, k=quad*8+j is a contiguous ds_read_b128).
// A-frag: A[m=lane&15][k=quad*8+j]; C/D: col=lane&15, row=quad*4+reg (m89/m120).
template<int K, bool PAIR>
__global__ __launch_bounds__(256) void k_mfma(const float* __restrict__ A,
                                              const float* __restrict__ Wl, const float* __restrict__ bl,
                                              const float* __restrict__ Wr, const float* __restrict__ br,
                                              float* __restrict__ XL, float* __restrict__ XR){
    constexpr int KC  = 32;
    constexpr int LDS_K = KC + 8;      // 40 shorts (80B rows, 16B-aligned, bank-spread)
    constexpr int NCH = K / KC;
    __shared__ short As_hi[64*LDS_K], As_lo[64*LDS_K];
    __shared__ short Wlh[64*LDS_K],  Wll[64*LDS_K];
    __shared__ short Wrh[64*LDS_K],  Wrl[64*LDS_K];

    int t = threadIdx.x;
    int lane = t & 63, wave = t >> 6;
    int quad = lane >> 4, ml = lane & 15;
    int rbase = blockIdx.x * 64;
    int nbase = blockIdx.y * 64;

    f32x4 accL[4], accR[4];
    #pragma unroll
    for(int i=0;i<4;i++){ accL[i] = (f32x4){0.f,0.f,0.f,0.f}; accR[i] = (f32x4){0.f,0.f,0.f,0.f}; }

    for(int c=0; c<NCH; c++){
        if(c) __syncthreads();
        // ---- stage A chunk: 64 rows x 32 cols fp32 -> hi/lo bf16 ----
        {
            int r = t >> 2, seg = t & 3;          // 8 floats per thread
            int gr = rbase + r; if(gr >= N_NODES) gr = N_NODES-1;
            const float* src = A + (size_t)gr*K + c*KC + seg*8;
            float4 f0 = *(const float4*)src;
            float4 f1 = *(const float4*)(src+4);
            float fs[8] = {f0.x,f0.y,f0.z,f0.w,f1.x,f1.y,f1.z,f1.w};
            short8 vh, vl;
            #pragma unroll
            for(int j=0;j<8;j++){ short h,l; split2(fs[j],h,l); vh[j]=h; vl[j]=l; }
            *(short8*)(As_hi + r*LDS_K + seg*8) = vh;
            *(short8*)(As_lo + r*LDS_K + seg*8) = vl;
        }
        // ---- stage W chunk(s): rows c*32..+32, cols nbase..+64, transposed ----
        {
            int n = t & 63, kq = t >> 6;          // 8 elems per thread per array
            #pragma unroll
            for(int p=0;p<8;p++){
                int kl = kq + p*4;
                short h,l;
                split2(Wl[(size_t)(c*KC + kl)*HC_DIM + nbase + n], h, l);
                Wlh[n*LDS_K + kl] = h; Wll[n*LDS_K + kl] = l;
                if(PAIR){
                    split2(Wr[(size_t)(c*KC + kl)*HC_DIM + nbase + n], h, l);
                    Wrh[n*LDS_K + kl] = h; Wrl[n*LDS_K + kl] = l;
                }
            }
        }
        __syncthreads();
        // ---- fragments + MFMA ----
        int k0 = quad*8;
        short8 wlh = *(const short8*)(Wlh + (wave*16 + ml)*LDS_K + k0);
        short8 wll = *(const short8*)(Wll + (wave*16 + ml)*LDS_K + k0);
        short8 wrh, wrl;
        if(PAIR){
            wrh = *(const short8*)(Wrh + (wave*16 + ml)*LDS_K + k0);
            wrl = *(const short8*)(Wrl + (wave*16 + ml)*LDS_K + k0);
        }
        #pragma unroll
        for(int i=0;i<4;i++){
            short8 ah = *(const short8*)(As_hi + (16*i + ml)*LDS_K + k0);
            short8 al = *(const short8*)(As_lo + (16*i + ml)*LDS_K + k0);
            accL[i] = __builtin_amdgcn_mfma_f32_16x16x32_bf16(ah, wlh, accL[i], 0,0,0);
            accL[i] = __builtin_amdgcn_mfma_f32_16x16x32_bf16(ah, wll, accL[i], 0,0,0);
            accL[i] = __builtin_amdgcn_mfma_f32_16x16x32_bf16(al, wlh, accL[i], 0,0,0);
            if(PAIR){
                accR[i] = __builtin_amdgcn_mfma_f32_16x16x32_bf16(ah, wrh, accR[i], 0,0,0);
                accR[i] = __builtin_amdgcn_mfma_f32_16x16x32_bf16(ah, wrl, accR[i], 0,0,0);
                accR[i] = __builtin_amdgcn_mfma_f32_16x16x32_bf16(al, wrh, accR[i], 0,0,0);
            }
        }
    }

    int col = nbase + wave*16 + ml;
    float bL = bl[col];
    float bR = PAIR ? br[col] : 0.f;
    #pragma unroll
    for(int i=0;i<4;i++){
        int row0 = rbase + 16*i + quad*4;
        #pragma unroll
        for(int r=0;r<4;r++){
            int gr = row0 + r;
            if(gr < N_NODES){
                XL[(size_t)gr*HC_DIM + col] = accL[i][r] + bL;
                if(PAIR) XR[(size_t)gr*HC_DIM + col] = accR[i][r] + bR;
            }
        }
    }
}

// row L2-normalize: out[r] = tmp[r]/max(||tmp[r]||,1e-12). one wave per row.
__global__ __launch_bounds__(256) void k_rownorm(const float* __restrict__ tmp, float* __restrict__ out){
    int wave=threadIdx.x>>6, lane=threadIdx.x&63;
    int node = blockIdx.x*4+wave;
    float2 v = *(const float2*)(tmp + (size_t)node*HC_DIM + 2*lane);
    float ss = v.x*v.x + v.y*v.y;
    #pragma unroll
    for(int msk=1;msk<64;msk<<=1) ss += __shfl_xor(ss,msk);
    float inv = 1.0f / fmaxf(sqrtf(ss), 1e-12f);
    *(float2*)(out + (size_t)node*HC_DIM + 2*lane) = make_float2(v.x*inv, v.y*inv);
}

// fused per-node GATv2: one wave per node. Lane layout: cg = lane&31 owns channels
// [4cg..4cg+4) (float4), half = lane>>5 owns alternate edges. Head = cg>>3; the
// head-dot reduction is 3 shfls over 8 lanes serving 2 edges per instruction.
// Two half-wave online-softmax states merge at end.
__global__ __launch_bounds__(256) void k_node(const float* __restrict__ XL, const float* __restrict__ XR,
    const int* __restrict__ rowptr, const int* __restrict__ colidx,
    const float* __restrict__ att, const float* __restrict__ bo,
    const float* __restrict__ gg, const float* __restrict__ be,
    const float* __restrict__ hold, float* __restrict__ hout)
{
    int wave=threadIdx.x>>6, lane=threadIdx.x&63;
    int node = blockIdx.x*4+wave;
    int cg = lane & 31, half = lane >> 5;
    int c4 = cg << 2;

    float4 xl = *(const float4*)(XL + (size_t)node*HC_DIM + c4);
    float4 av = *(const float4*)(att + c4);
    int beg = rowptr[node], end = rowptr[node+1];

    #define EDGE_LOGIT(xj, q) { \
        float u0 = xl.x + xj.x; u0 = (u0>0.f)?u0:0.2f*u0; \
        float u1 = xl.y + xj.y; u1 = (u1>0.f)?u1:0.2f*u1; \
        float u2 = xl.z + xj.z; u2 = (u2>0.f)?u2:0.2f*u2; \
        float u3 = xl.w + xj.w; u3 = (u3>0.f)?u3:0.2f*u3; \
        q = fmaf(u0,av.x, fmaf(u1,av.y, fmaf(u2,av.z, u3*av.w))); \
        q += __shfl_xor(q,1); q += __shfl_xor(q,2); q += __shfl_xor(q,4); }

    // self-loop seeds half 0; half 1 starts empty
    float4 xs = *(const float4*)(XR + (size_t)node*HC_DIM + c4);
    float qs; EDGE_LOGIT(xs, qs)
    float m, ls; float4 acc;
    if(half==0){ m = qs; ls = 1.f; acc = xs; }
    else       { m = -INFINITY; ls = 0.f; acc = make_float4(0.f,0.f,0.f,0.f); }

    int P = end - beg;
    int nb = P >> 3;
    int base = beg;
    for(int b=0; b<nb; b++, base += 8){
        int j0 = colidx[base     + half];
        int j1 = colidx[base + 2 + half];
        int j2 = colidx[base + 4 + half];
        int j3 = colidx[base + 6 + half];
        float4 x0 = *(const float4*)(XR + (size_t)j0*HC_DIM + c4);
        float4 x1 = *(const float4*)(XR + (size_t)j1*HC_DIM + c4);
        float4 x2 = *(const float4*)(XR + (size_t)j2*HC_DIM + c4);
        float4 x3 = *(const float4*)(XR + (size_t)j3*HC_DIM + c4);
        float q0,q1,q2,q3;
        EDGE_LOGIT(x0,q0) EDGE_LOGIT(x1,q1) EDGE_LOGIT(x2,q2) EDGE_LOGIT(x3,q3)
        float nm = fmaxf(m, fmaxf(fmaxf(q0,q1),fmaxf(q2,q3)));
        float sc = __expf(m-nm);
        float e0 = __expf(q0-nm), e1 = __expf(q1-nm);
        float e2 = __expf(q2-nm), e3 = __expf(q3-nm);
        ls = fmaf(ls, sc, (e0+e1)+(e2+e3));
        acc.x = fmaf(acc.x, sc, fmaf(e0,x0.x, fmaf(e1,x1.x, fmaf(e2,x2.x, e3*x3.x))));
        acc.y = fmaf(acc.y, sc, fmaf(e0,x0.y, fmaf(e1,x1.y, fmaf(e2,x2.y, e3*x3.y))));
        acc.z = fmaf(acc.z, sc, fmaf(e0,x0.z, fmaf(e1,x1.z, fmaf(e2,x2.z, e3*x3.z))));
        acc.w = fmaf(acc.w, sc, fmaf(e0,x0.w, fmaf(e1,x1.w, fmaf(e2,x2.w, e3*x3.w))));
        m = nm;
    }
    // tail: up to 7 edges, alternate halves
    #pragma unroll
    for(int i=0;i<4;i++){
        int idx = base + 2*i + half;
        if(idx < end){
            int j = colidx[idx];
            float4 xj = *(const float4*)(XR + (size_t)j*HC_DIM + c4);
            float q; EDGE_LOGIT(xj, q)
            float nm = fmaxf(m, q);
            float sc = __expf(m-nm);
            float p  = __expf(q-nm);
            ls = fmaf(ls, sc, p);
            acc.x = fmaf(acc.x, sc, p*xj.x);
            acc.y = fmaf(acc.y, sc, p*xj.y);
            acc.z = fmaf(acc.z, sc, p*xj.z);
            acc.w = fmaf(acc.w, sc, p*xj.w);
            m = nm;
        }
    }
    #undef EDGE_LOGIT

    // merge the two half-wave softmax states
    {
        float mo  = __shfl_xor(m, 32);
        float lso = __shfl_xor(ls, 32);
        float4 ao;
        ao.x = __shfl_xor(acc.x,32); ao.y = __shfl_xor(acc.y,32);
        ao.z = __shfl_xor(acc.z,32); ao.w = __shfl_xor(acc.w,32);
        float nm = fmaxf(m, mo);
        float s0 = __expf(m-nm), s1 = __expf(mo-nm);
        ls = ls*s0 + lso*s1;
        acc.x = acc.x*s0 + ao.x*s1;
        acc.y = acc.y*s0 + ao.y*s1;
        acc.z = acc.z*s0 + ao.z*s1;
        acc.w = acc.w*s0 + ao.w*s1;
    }

    float inv = 1.0f/ls;
    float4 bo4 = *(const float4*)(bo + c4);
    float o0 = fmaf(acc.x,inv,bo4.x), o1 = fmaf(acc.y,inv,bo4.y);
    float o2 = fmaf(acc.z,inv,bo4.z), o3 = fmaf(acc.w,inv,bo4.w);
    float s1v = (o0+o1)+(o2+o3);
    float s2v = fmaf(o0,o0, fmaf(o1,o1, fmaf(o2,o2, o3*o3)));
    #pragma unroll
    for(int msk=1;msk<32;msk<<=1){ s1v += __shfl_xor(s1v,msk); s2v += __shfl_xor(s2v,msk); }
    float mean = s1v*(1.f/128.f);
    float var  = s2v*(1.f/128.f) - mean*mean;
    float rstd = rsqrtf(var + 1e-5f);
    float4 g4  = *(const float4*)(gg + c4);
    float4 be4 = *(const float4*)(be + c4);
    float r0 = gelu_f(fmaf(g4.x*(o0-mean), rstd, be4.x));
    float r1 = gelu_f(fmaf(g4.y*(o1-mean), rstd, be4.y));
    float r2 = gelu_f(fmaf(g4.z*(o2-mean), rstd, be4.z));
    float r3 = gelu_f(fmaf(g4.w*(o3-mean), rstd, be4.w));
    if(hold){
        float4 hv = *(const float4*)(hold + (size_t)node*HC_DIM + c4);
        r0 += hv.x; r1 += hv.y; r2 += hv.z; r3 += hv.w;
    }
    if(half==0)
        *(float4*)(hout + (size_t)node*HC_DIM + c4) = make_float4(r0,r1,r2,r3);
}

extern "C" void kernel_launch(void* const* d_in, const int* in_sizes, int n_in,
                              void* d_out, int out_size, void* d_ws, size_t ws_size,
                              hipStream_t stream)
{
    const float* x   = (const float*)d_in[0];
    const int*   ei  = (const int*)  d_in[1];
    const float* Win = (const float*)d_in[2];
    const float* bin = (const float*)d_in[3];
    const float *Wl[3], *bl[3], *Wr[3], *br[3], *att[3], *bo[3], *gg[3], *be[3];
    for(int i=0;i<3;i++){
        const int base = 4 + 8*i;
        Wl[i]=(const float*)d_in[base+0]; bl[i]=(const float*)d_in[base+1];
        Wr[i]=(const float*)d_in[base+2]; br[i]=(const float*)d_in[base+3];
        att[i]=(const float*)d_in[base+4]; bo[i]=(const float*)d_in[base+5];
        gg[i]=(const float*)d_in[base+6]; be[i]=(const float*)d_in[base+7];
    }
    const float* Wout=(const float*)d_in[28];
    const float* bout=(const float*)d_in[29];
    float* out = (float*)d_out;

    char* w = (char*)d_ws;
    float* hA = (float*)w;  w += (size_t)N_NODES*HC_DIM*4;
    float* hB = (float*)w;  w += (size_t)N_NODES*HC_DIM*4;
    float* XL = (float*)w;  w += (size_t)N_NODES*HC_DIM*4;
    float* XR = (float*)w;  w += (size_t)N_NODES*HC_DIM*4;
    int* rowptr = (int*)w;  w += (size_t)(N_NODES+2)*4;
    int* cursor = (int*)w;  w += (size_t)N_NODES*4;
    int* colidx = (int*)w;  w += (size_t)N_EDGES*4;
    int* part   = (int*)w;  w += 256*4;

    const int* srcp = ei;
    const int* dstp = ei + N_EDGES;

    const dim3 gemm_grid(782, 2);   // 782 row-tiles x 2 col-strips of 64

    // ---- CSR by destination (built once, reused by all 3 layers) ----
    k_zero  <<<196, 256, 0, stream>>>(cursor, N_NODES);
    k_count <<<3125,256, 0, stream>>>(dstp, cursor);
    k_scan1 <<<SCAN_NB,256,0,stream>>>(cursor, rowptr, part);
    k_scan2 <<<1,   256, 0, stream>>>(part);
    k_scan3 <<<SCAN_NB,256,0,stream>>>(rowptr, part, cursor);
    k_fill  <<<3125,256, 0, stream>>>(srcp, dstp, cursor, colidx);

    // ---- input projection ----
    k_gemm_in<<<6250,256,0,stream>>>(x, Win, bin, hA);

    // ---- layer 0: hA[N,32] -> hB[N,128] (no residual) ----
    k_mfma<32,true><<<gemm_grid,256,0,stream>>>(hA, Wl[0], bl[0], Wr[0], br[0], XL, XR);
    k_node<<<12500,256,0,stream>>>(XL,XR,rowptr,colidx,att[0],bo[0],gg[0],be[0], (const float*)nullptr, hB);

    // ---- layer 1: hB -> hA (residual hB) ----
    k_mfma<128,true><<<gemm_grid,256,0,stream>>>(hB, Wl[1], bl[1], Wr[1], br[1], XL, XR);
    k_node<<<12500,256,0,stream>>>(XL,XR,rowptr,colidx,att[1],bo[1],gg[1],be[1], hB, hA);

    // ---- layer 2: hA -> hB (residual hA) ----
    k_mfma<128,true><<<gemm_grid,256,0,stream>>>(hA, Wl[2], bl[2], Wr[2], br[2], XL, XR);
    k_node<<<12500,256,0,stream>>>(XL,XR,rowptr,colidx,att[2],bo[2],gg[2],be[2], hA, hB);

    // ---- output projection (MFMA -> XL as tmp) + row L2-normalize ----
    k_mfma<128,false><<<gemm_grid,256,0,stream>>>(hB, Wout, bout, nullptr, nullptr, XL, nullptr);
    k_rownorm<<<12500,256,0,stream>>>(XL, out);
}